// Round 6
// baseline (1207.765 us; speedup 1.0000x reference)
//
#include <hip/hip_runtime.h>
#include <hip/hip_bf16.h>
#include <math.h>

// TemporalTransformerConv (TGAT-like) for MI355X — round 6.
// Counting-sort CSR by edge_dst + dst-centric fused edge pass:
// per-wave 16 dsts, register accumulation of softmax num/den, single
// normalized write per dst. Zero atomics in the hot kernel.
// Dsts processed in count-sorted (descending) order -> equal-length
// segments per tile (no padding) + long segments scheduled first.

using bf16 = __hip_bfloat16;
typedef __attribute__((ext_vector_type(8))) short short8;
typedef __attribute__((ext_vector_type(4))) float f32x4;

static __device__ __forceinline__ unsigned short bf16_bits(float x) {
    bf16 h = __float2bfloat16(x);
    unsigned short b;
    __builtin_memcpy(&b, &h, 2);
    return b;
}
static __device__ __forceinline__ unsigned pk2(float x, float y) {
    return (unsigned)bf16_bits(x) | ((unsigned)bf16_bits(y) << 16);
}
union frag_u { short8 s; unsigned u[4]; };

// ------------------------- prep -------------------------
__global__ void k_prep(float* qbias, const float* __restrict__ wq_w,
                       const float* __restrict__ wq_b, const float* __restrict__ time_b) {
    int c = threadIdx.x;
    if (c < 128) {
        float s = wq_b[c];
        for (int j = 0; j < 64; ++j)
            s += cosf(time_b[j]) * wq_w[(128 + j) * 128 + c];
        qbias[c] = s;
    }
}

// pack wk_w/wv_w (256x128 f32, k-major) -> bf16 transposed [n][k] (128x256)
__global__ void k_pack(unsigned short* wkT, unsigned short* wvT,
                       const float* __restrict__ wk_w, const float* __restrict__ wv_w) {
    int idx = blockIdx.x * blockDim.x + threadIdx.x;  // 32768
    if (idx < 32768) {
        int n = idx >> 8, k = idx & 255;
        wkT[idx] = bf16_bits(wk_w[(size_t)k * 128 + n]);
        wvT[idx] = bf16_bits(wv_w[(size_t)k * 128 + n]);
    }
}

// ------------------------- sort (CSR build) -------------------------
__global__ void k_zero(int* cnt, int* fill, int* hist, int* hfill, int n) {
    int i = blockIdx.x * blockDim.x + threadIdx.x;
    int stride = gridDim.x * blockDim.x;
    for (; i < n; i += stride) {
        cnt[i] = 0; fill[i] = 0;
        if (i < 256) { hist[i] = 0; hfill[i] = 0; }
    }
}

__global__ void k_count(const int* __restrict__ edst, int* cnt, int E) {
    int e = blockIdx.x * 256 + threadIdx.x;
    if (e < E) atomicAdd(&cnt[edst[e]], 1);
}

// block-level exclusive scan (256/block)
__global__ void k_scan1(const int* __restrict__ cnt, int* rs, int* bsum, int n) {
    __shared__ int s[256];
    int t = threadIdx.x;
    int i = blockIdx.x * 256 + t;
    int v = (i < n) ? cnt[i] : 0;
    s[t] = v;
    __syncthreads();
    for (int off = 1; off < 256; off <<= 1) {
        int x = (t >= off) ? s[t - off] : 0;
        __syncthreads();
        s[t] += x;
        __syncthreads();
    }
    if (i < n) rs[i] = s[t] - v;
    if (t == 255) bsum[blockIdx.x] = s[255];
}

// single-block exclusive scan of block sums (nblk <= 256)
__global__ void k_scan2(int* bsum, int nblk) {
    __shared__ int s[256];
    int t = threadIdx.x;
    int v = (t < nblk) ? bsum[t] : 0;
    s[t] = v;
    __syncthreads();
    for (int off = 1; off < 256; off <<= 1) {
        int x = (t >= off) ? s[t - off] : 0;
        __syncthreads();
        s[t] += x;
        __syncthreads();
    }
    if (t < nblk) bsum[t] = s[t] - v;
}

__global__ void k_scan3(int* rs, const int* __restrict__ bsum, int n) {
    int i = blockIdx.x * 256 + threadIdx.x;
    if (i < n) rs[i] += bsum[blockIdx.x];
}

__global__ void k_scatter(const int* __restrict__ edst, const int* __restrict__ rs,
                          int* fill, int* eord, int E) {
    int e = blockIdx.x * 256 + threadIdx.x;
    if (e < E) {
        int d = edst[e];
        int p = rs[d] + atomicAdd(&fill[d], 1);
        eord[p] = e;
    }
}

__global__ void k_hist(const int* __restrict__ cnt, int* hist, int n) {
    int d = blockIdx.x * 256 + threadIdx.x;
    if (d < n) atomicAdd(&hist[min(cnt[d], 255)], 1);
}

// exclusive suffix sum: hist[b] <- sum of hist[b'] for b' > b  (descending starts)
__global__ void k_hsuf(int* hist) {
    __shared__ int s[256];
    int t = threadIdx.x;
    int v = hist[t];
    s[t] = v;
    __syncthreads();
    for (int off = 1; off < 256; off <<= 1) {
        int x = (t + off < 256) ? s[t + off] : 0;
        __syncthreads();
        s[t] += x;
        __syncthreads();
    }
    hist[t] = s[t] - v;
}

__global__ void k_dorder(const int* __restrict__ cnt, const int* __restrict__ hstart,
                         int* hfill, int* dorder, int n) {
    int d = blockIdx.x * 256 + threadIdx.x;
    if (d < n) {
        int b = min(cnt[d], 255);
        int p = hstart[b] + atomicAdd(&hfill[b], 1);
        dorder[p] = d;
    }
}

// ------------------------- Q projection -------------------------
__global__ __launch_bounds__(256) void k_q(
    float* __restrict__ Q, const float* __restrict__ h,
    const float* __restrict__ wq_w, const float* __restrict__ qbias, int ndst)
{
    __shared__ float As[64 * 128];
    int row0 = blockIdx.x * 64;
    int tid = threadIdx.x;
    for (int idx = tid; idx < 64 * 128; idx += 256) {
        int r = idx >> 7, c = idx & 127;
        int gr = row0 + r;
        As[idx] = (gr < ndst) ? h[(size_t)gr * 128 + c] : 0.f;
    }
    __syncthreads();
    int cg = tid & 31, rg = tid >> 5;
    int c0 = cg * 4;
    float acc[8][4];
    #pragma unroll
    for (int i = 0; i < 8; ++i) { acc[i][0]=0.f; acc[i][1]=0.f; acc[i][2]=0.f; acc[i][3]=0.f; }
    for (int k = 0; k < 128; k += 4) {
        float4 w0 = *reinterpret_cast<const float4*>(wq_w + (size_t)(k+0)*128 + c0);
        float4 w1 = *reinterpret_cast<const float4*>(wq_w + (size_t)(k+1)*128 + c0);
        float4 w2 = *reinterpret_cast<const float4*>(wq_w + (size_t)(k+2)*128 + c0);
        float4 w3 = *reinterpret_cast<const float4*>(wq_w + (size_t)(k+3)*128 + c0);
        #pragma unroll
        for (int i = 0; i < 8; ++i) {
            float4 a = *reinterpret_cast<const float4*>(&As[(rg*8+i)*128 + k]);
            acc[i][0] = fmaf(a.x,w0.x,fmaf(a.y,w1.x,fmaf(a.z,w2.x,fmaf(a.w,w3.x,acc[i][0]))));
            acc[i][1] = fmaf(a.x,w0.y,fmaf(a.y,w1.y,fmaf(a.z,w2.y,fmaf(a.w,w3.y,acc[i][1]))));
            acc[i][2] = fmaf(a.x,w0.z,fmaf(a.y,w1.z,fmaf(a.z,w2.z,fmaf(a.w,w3.z,acc[i][2]))));
            acc[i][3] = fmaf(a.x,w0.w,fmaf(a.y,w1.w,fmaf(a.z,w2.w,fmaf(a.w,w3.w,acc[i][3]))));
        }
    }
    float q0 = qbias[c0], q1 = qbias[c0+1], q2 = qbias[c0+2], q3 = qbias[c0+3];
    #pragma unroll
    for (int i = 0; i < 8; ++i) {
        int r = row0 + rg*8 + i;
        if (r < ndst) {
            float4 o = make_float4(acc[i][0]+q0, acc[i][1]+q1, acc[i][2]+q2, acc[i][3]+q3);
            *reinterpret_cast<float4*>(Q + (size_t)r*128 + c0) = o;
        }
    }
}

// ------------------------- fused dst-centric edge pass -------------------------
// Wave owns 16 dsts (rows). Loop i over edge streams; MFMA K/V tiles via direct
// per-lane gathers; register softmax accumulation; one normalized write per dst.
__global__ __launch_bounds__(256) void k_kv_dst(
    const float* __restrict__ h, const int* __restrict__ nbr,
    const float* __restrict__ dt, const float* __restrict__ ef,
    const float* __restrict__ time_w, const float* __restrict__ time_b,
    const unsigned short* __restrict__ wkT, const unsigned short* __restrict__ wvT,
    const float* __restrict__ wk_b, const float* __restrict__ wv_b,
    const float* __restrict__ Q, const int* __restrict__ dorder,
    const int* __restrict__ rs, const int* __restrict__ cnt,
    const int* __restrict__ eord, float* __restrict__ agg, int ndst, int E)
{
    int tid  = threadIdx.x;
    int lane = tid & 63;
    int l15  = lane & 15;
    int lk   = lane >> 4;
    int wb   = (blockIdx.x * 4 + (tid >> 6)) * 16;
    if (wb >= ndst) return;

    // A-side edge stream identity for row l15
    int rA   = wb + l15;
    int dA   = (rA < ndst) ? dorder[rA] : 0;
    int rsA  = (rA < ndst) ? rs[dA] : 0;

    // D rows (lk*4+j) with their dsts and counts
    int dstr[4]; int cntD[4];
    #pragma unroll
    for (int j = 0; j < 4; ++j) {
        int r = wb + lk * 4 + j;
        if (r < ndst) { dstr[j] = dorder[r]; cntD[j] = cnt[dstr[j]]; }
        else          { dstr[j] = -1;        cntD[j] = 0; }
    }
    // wave-uniform max count (rows share l15 pattern across lk groups)
    int cm = (rA < ndst) ? cnt[dA] : 0;
    #pragma unroll
    for (int m = 1; m <= 8; m <<= 1) {
        int o = __shfl_xor(cm, m, 64);
        cm = (o > cm) ? o : cm;
    }

    // hoisted: Q for the 16 dsts, biases
    float qg[8][4];
    #pragma unroll
    for (int nt = 0; nt < 8; ++nt) {
        int gc = nt * 16 + l15;
        #pragma unroll
        for (int j = 0; j < 4; ++j)
            qg[nt][j] = (dstr[j] >= 0) ? Q[(size_t)dstr[j] * 128 + gc] : 0.f;
    }
    float kb[8], vbv[8];
    #pragma unroll
    for (int nt = 0; nt < 8; ++nt) {
        kb[nt]  = wk_b[nt * 16 + l15];
        vbv[nt] = wv_b[nt * 16 + l15];
    }

    float cva[8][4];
    float dn0[4], dn1[4];
    #pragma unroll
    for (int nt = 0; nt < 8; ++nt)
        #pragma unroll
        for (int j = 0; j < 4; ++j) cva[nt][j] = 0.f;
    #pragma unroll
    for (int j = 0; j < 4; ++j) { dn0[j] = 0.f; dn1[j] = 0.f; }

    for (int i = 0; i < cm; ++i) {
        // ---- gather A fragments for edge = i-th edge of dst(row l15) ----
        int idx = rsA + i; idx = (idx < E - 1) ? idx : E - 1;
        int e = eord[idx];
        int na = nbr[e];
        float da = dt[e];
        const float* hrow = h + (size_t)(ndst + na) * 128;
        const float* erow = ef + (size_t)e * 64;
        frag_u a[8];
        #pragma unroll
        for (int kk = 0; kk < 8; ++kk) {
            int c0 = kk * 32 + lk * 8;
            if (kk < 4) {
                float4 x = *reinterpret_cast<const float4*>(hrow + c0);
                float4 y = *reinterpret_cast<const float4*>(hrow + c0 + 4);
                a[kk].u[0] = pk2(x.x, x.y); a[kk].u[1] = pk2(x.z, x.w);
                a[kk].u[2] = pk2(y.x, y.y); a[kk].u[3] = pk2(y.z, y.w);
            } else if (kk < 6) {
                int c = c0 - 128;
                float4 x = *reinterpret_cast<const float4*>(erow + c);
                float4 y = *reinterpret_cast<const float4*>(erow + c + 4);
                a[kk].u[0] = pk2(x.x, x.y); a[kk].u[1] = pk2(x.z, x.w);
                a[kk].u[2] = pk2(y.x, y.y); a[kk].u[3] = pk2(y.z, y.w);
            } else {
                int j0 = c0 - 192;
                float v[8];
                #pragma unroll
                for (int t = 0; t < 8; ++t)
                    v[t] = __cosf(fmaf(da, time_w[j0 + t], time_b[j0 + t]));
                a[kk].u[0] = pk2(v[0], v[1]); a[kk].u[1] = pk2(v[2], v[3]);
                a[kk].u[2] = pk2(v[4], v[5]); a[kk].u[3] = pk2(v[6], v[7]);
            }
        }

        // ---- K GEMM ----
        f32x4 ck[8];
        #pragma unroll
        for (int nt = 0; nt < 8; ++nt) ck[nt] = (f32x4){0.f, 0.f, 0.f, 0.f};
        #pragma unroll
        for (int kk = 0; kk < 8; ++kk)
            #pragma unroll
            for (int nt = 0; nt < 8; ++nt) {
                short8 b = *reinterpret_cast<const short8*>(
                    wkT + (size_t)(nt * 16 + l15) * 256 + kk * 32 + lk * 8);
                ck[nt] = __builtin_amdgcn_mfma_f32_16x16x32_bf16(a[kk].s, b, ck[nt], 0, 0, 0);
            }

        // ---- att dot + 16-lane reduce ----
        float p0[4], p1[4];
        #pragma unroll
        for (int j = 0; j < 4; ++j) { p0[j] = 0.f; p1[j] = 0.f; }
        #pragma unroll
        for (int nt = 0; nt < 8; ++nt)
            #pragma unroll
            for (int j = 0; j < 4; ++j) {
                float t = (ck[nt][j] + kb[nt]) * qg[nt][j];
                if (nt < 4) p0[j] += t; else p1[j] += t;
            }
        #pragma unroll
        for (int m = 1; m <= 8; m <<= 1)
            #pragma unroll
            for (int j = 0; j < 4; ++j) {
                p0[j] += __shfl_xor(p0[j], m, 64);
                p1[j] += __shfl_xor(p1[j], m, 64);
            }
        float e0[4], e1[4];
        #pragma unroll
        for (int j = 0; j < 4; ++j) {
            float r0 = p0[j]; r0 = (r0 >= 0.f) ? r0 : 0.2f * r0;
            float r1 = p1[j]; r1 = (r1 >= 0.f) ? r1 : 0.2f * r1;
            bool valid = (i < cntD[j]);
            e0[j] = valid ? __expf(r0) : 0.f;
            e1[j] = valid ? __expf(r1) : 0.f;
            dn0[j] += e0[j]; dn1[j] += e1[j];
        }

        // ---- V GEMM ----
        f32x4 cv[8];
        #pragma unroll
        for (int nt = 0; nt < 8; ++nt) cv[nt] = (f32x4){0.f, 0.f, 0.f, 0.f};
        #pragma unroll
        for (int kk = 0; kk < 8; ++kk)
            #pragma unroll
            for (int nt = 0; nt < 8; ++nt) {
                short8 b = *reinterpret_cast<const short8*>(
                    wvT + (size_t)(nt * 16 + l15) * 256 + kk * 32 + lk * 8);
                cv[nt] = __builtin_amdgcn_mfma_f32_16x16x32_bf16(a[kk].s, b, cv[nt], 0, 0, 0);
            }
        // ---- weighted register accumulation ----
        #pragma unroll
        for (int nt = 0; nt < 8; ++nt)
            #pragma unroll
            for (int j = 0; j < 4; ++j) {
                float s = (nt < 4) ? e0[j] : e1[j];
                cva[nt][j] = fmaf(s, cv[nt][j] + vbv[nt], cva[nt][j]);
            }
    }

    // ---- normalized single write per dst ----
    #pragma unroll
    for (int nt = 0; nt < 8; ++nt) {
        int gc = nt * 16 + l15;
        #pragma unroll
        for (int j = 0; j < 4; ++j)
            if (dstr[j] >= 0) {
                float dd = (nt < 4) ? dn0[j] : dn1[j];
                agg[(size_t)dstr[j] * 128 + gc] = (dd > 0.f) ? cva[nt][j] / dd : 0.f;
            }
    }
}

// ------------------------- output: GEMM + ReLU + LayerNorm -------------------------
__global__ __launch_bounds__(256) void k_out(
    const float* __restrict__ agg,
    const float* __restrict__ h, const float* __restrict__ wo_w, const float* __restrict__ wo_b,
    const float* __restrict__ ln_g, const float* __restrict__ ln_b,
    float* __restrict__ out, int ndst)
{
    __shared__ float As[64 * 256];
    int row0 = blockIdx.x * 64;
    int tid = threadIdx.x;
    for (int idx = tid; idx < 64 * 256; idx += 256) {
        int r = idx >> 8, c = idx & 255;
        int gr = row0 + r;
        float v = 0.f;
        if (gr < ndst)
            v = (c < 128) ? agg[(size_t)gr * 128 + c] : h[(size_t)gr * 128 + (c - 128)];
        As[idx] = v;
    }
    __syncthreads();
    int cg = tid & 31, rg = tid >> 5;
    int c0 = cg * 4;
    float acc[8][4];
    #pragma unroll
    for (int i = 0; i < 8; ++i) { acc[i][0]=0.f; acc[i][1]=0.f; acc[i][2]=0.f; acc[i][3]=0.f; }
    for (int k = 0; k < 256; k += 4) {
        float4 w0 = *reinterpret_cast<const float4*>(wo_w + (size_t)(k+0)*128 + c0);
        float4 w1 = *reinterpret_cast<const float4*>(wo_w + (size_t)(k+1)*128 + c0);
        float4 w2 = *reinterpret_cast<const float4*>(wo_w + (size_t)(k+2)*128 + c0);
        float4 w3 = *reinterpret_cast<const float4*>(wo_w + (size_t)(k+3)*128 + c0);
        #pragma unroll
        for (int i = 0; i < 8; ++i) {
            float4 a = *reinterpret_cast<const float4*>(&As[(rg*8+i)*256 + k]);
            acc[i][0] = fmaf(a.x,w0.x,fmaf(a.y,w1.x,fmaf(a.z,w2.x,fmaf(a.w,w3.x,acc[i][0]))));
            acc[i][1] = fmaf(a.x,w0.y,fmaf(a.y,w1.y,fmaf(a.z,w2.y,fmaf(a.w,w3.y,acc[i][1]))));
            acc[i][2] = fmaf(a.x,w0.z,fmaf(a.y,w1.z,fmaf(a.z,w2.z,fmaf(a.w,w3.z,acc[i][2]))));
            acc[i][3] = fmaf(a.x,w0.w,fmaf(a.y,w1.w,fmaf(a.z,w2.w,fmaf(a.w,w3.w,acc[i][3]))));
        }
    }
    float b0 = wo_b[c0], b1 = wo_b[c0+1], b2 = wo_b[c0+2], b3 = wo_b[c0+3];
    float g0 = ln_g[c0], g1 = ln_g[c0+1], g2 = ln_g[c0+2], g3 = ln_g[c0+3];
    float l0 = ln_b[c0], l1 = ln_b[c0+1], l2 = ln_b[c0+2], l3 = ln_b[c0+3];
    #pragma unroll
    for (int i = 0; i < 8; ++i) {
        float x0 = fmaxf(acc[i][0] + b0, 0.f);
        float x1 = fmaxf(acc[i][1] + b1, 0.f);
        float x2 = fmaxf(acc[i][2] + b2, 0.f);
        float x3 = fmaxf(acc[i][3] + b3, 0.f);
        float s1 = x0 + x1 + x2 + x3;
        float s2 = x0*x0 + x1*x1 + x2*x2 + x3*x3;
        #pragma unroll
        for (int mm = 1; mm <= 16; mm <<= 1) {
            s1 += __shfl_xor(s1, mm, 64);
            s2 += __shfl_xor(s2, mm, 64);
        }
        float mean = s1 * (1.f / 128.f);
        float var  = s2 * (1.f / 128.f) - mean * mean;
        float rstd = rsqrtf(var + 1e-5f);
        int r = row0 + rg * 8 + i;
        if (r < ndst) {
            float4 o = make_float4((x0 - mean) * rstd * g0 + l0,
                                   (x1 - mean) * rstd * g1 + l1,
                                   (x2 - mean) * rstd * g2 + l2,
                                   (x3 - mean) * rstd * g3 + l3);
            *reinterpret_cast<float4*>(out + (size_t)r * 128 + c0) = o;
        }
    }
}

extern "C" void kernel_launch(void* const* d_in, const int* in_sizes, int n_in,
                              void* d_out, int out_size, void* d_ws, size_t ws_size,
                              hipStream_t stream) {
    const float* h      = (const float*)d_in[0];
    const float* dt     = (const float*)d_in[1];
    const float* ef     = (const float*)d_in[2];
    const float* time_w = (const float*)d_in[3];
    const float* time_b = (const float*)d_in[4];
    const float* wq_w   = (const float*)d_in[5];
    const float* wq_b   = (const float*)d_in[6];
    const float* wk_w   = (const float*)d_in[7];
    const float* wk_b   = (const float*)d_in[8];
    const float* wv_w   = (const float*)d_in[9];
    const float* wv_b   = (const float*)d_in[10];
    const float* wo_w   = (const float*)d_in[11];
    const float* wo_b   = (const float*)d_in[12];
    const float* ln_g   = (const float*)d_in[13];
    const float* ln_b   = (const float*)d_in[14];
    const int* nbr      = (const int*)d_in[15];
    const int* edst     = (const int*)d_in[16];

    int E    = in_sizes[1];
    int ndst = out_size / 128;
    int nblk = (ndst + 255) / 256;   // scan blocks (<=256 assumed; 196 for 50k)

    char* wsb = (char*)d_ws;
    float* qbias = (float*)wsb;                           wsb += 512;
    float* Q     = (float*)wsb;                           wsb += (size_t)ndst * 128 * 4;
    float* agg   = (float*)wsb;                           wsb += (size_t)ndst * 128 * 4;
    unsigned short* wkT = (unsigned short*)wsb;           wsb += 32768 * 2;
    unsigned short* wvT = (unsigned short*)wsb;           wsb += 32768 * 2;
    int* cnt    = (int*)wsb;                              wsb += (size_t)ndst * 4;
    int* rs     = (int*)wsb;                              wsb += (size_t)ndst * 4;
    int* fill   = (int*)wsb;                              wsb += (size_t)ndst * 4;
    int* dorder = (int*)wsb;                              wsb += (size_t)ndst * 4;
    int* eord   = (int*)wsb;                              wsb += (size_t)E * 4;
    int* bsum   = (int*)wsb;                              wsb += 256 * 4;
    int* hist   = (int*)wsb;                              wsb += 256 * 4;
    int* hfill  = (int*)wsb;                              wsb += 256 * 4;
    // total ~54 MB

    k_zero<<<256, 256, 0, stream>>>(cnt, fill, hist, hfill, ndst);
    k_prep<<<1, 128, 0, stream>>>(qbias, wq_w, wq_b, time_b);
    k_pack<<<128, 256, 0, stream>>>(wkT, wvT, wk_w, wv_w);
    k_count<<<(E + 255) / 256, 256, 0, stream>>>(edst, cnt, E);
    k_scan1<<<nblk, 256, 0, stream>>>(cnt, rs, bsum, ndst);
    k_scan2<<<1, 256, 0, stream>>>(bsum, nblk);
    k_scan3<<<nblk, 256, 0, stream>>>(rs, bsum, ndst);
    k_scatter<<<(E + 255) / 256, 256, 0, stream>>>(edst, rs, fill, eord, E);
    k_hist<<<nblk, 256, 0, stream>>>(cnt, hist, ndst);
    k_hsuf<<<1, 256, 0, stream>>>(hist);
    k_dorder<<<nblk, 256, 0, stream>>>(cnt, hist, hfill, dorder, ndst);
    k_q<<<(ndst + 63) / 64, 256, 0, stream>>>(Q, h, wq_w, qbias, ndst);
    k_kv_dst<<<(ndst + 63) / 64, 256, 0, stream>>>(h, nbr, dt, ef, time_w, time_b,
                                                   wkT, wvT, wk_b, wv_b, Q, dorder,
                                                   rs, cnt, eord, agg, ndst, E);
    k_out<<<(ndst + 63) / 64, 256, 0, stream>>>(agg, h, wo_w, wo_b, ln_g, ln_b,
                                                (float*)d_out, ndst);
}

// Round 7
// 515.290 us; speedup vs baseline: 2.3439x; 2.3439x over previous
//
#include <hip/hip_runtime.h>
#include <hip/hip_bf16.h>
#include <math.h>

// TemporalTransformerConv (TGAT-like) for MI355X — round 7.
// Edge-centric MFMA writer (no atomics): V rows (bf16, col-permuted) + att
// scores written to dst-sorted slots via epos[]; then a fully-streaming
// segment-reduction kernel computes softmax-weighted agg per dst.
// ws: qbias | Q(25.6M) | agg(25.6M) | wkT/wvT(128K) | cnt/rs/fill(600K) |
//     epos(1M) | bsum | att2(2M) | Vbuf bf16(64M)  ~= 120 MB

using bf16 = __hip_bfloat16;
typedef __attribute__((ext_vector_type(8))) short short8;
typedef __attribute__((ext_vector_type(4))) float f32x4;

static __device__ __forceinline__ unsigned short bf16_bits(float x) {
    bf16 h = __float2bfloat16(x);
    unsigned short b;
    __builtin_memcpy(&b, &h, 2);
    return b;
}
static __device__ __forceinline__ unsigned pk2(float x, float y) {
    return (unsigned)bf16_bits(x) | ((unsigned)bf16_bits(y) << 16);
}
static __device__ __forceinline__ float bflo(unsigned u) {
    return __uint_as_float(u << 16);
}
static __device__ __forceinline__ float bfhi(unsigned u) {
    return __uint_as_float(u & 0xffff0000u);
}
union frag_u { short8 s; unsigned u[4]; };

// ------------------------- prep -------------------------
__global__ void k_prep(float* qbias, const float* __restrict__ wq_w,
                       const float* __restrict__ wq_b, const float* __restrict__ time_b) {
    int c = threadIdx.x;
    if (c < 128) {
        float s = wq_b[c];
        for (int j = 0; j < 64; ++j)
            s += cosf(time_b[j]) * wq_w[(128 + j) * 128 + c];
        qbias[c] = s;
    }
}

__global__ void k_pack(unsigned short* wkT, unsigned short* wvT,
                       const float* __restrict__ wk_w, const float* __restrict__ wv_w) {
    int idx = blockIdx.x * blockDim.x + threadIdx.x;  // 32768
    if (idx < 32768) {
        int n = idx >> 8, k = idx & 255;
        wkT[idx] = bf16_bits(wk_w[(size_t)k * 128 + n]);
        wvT[idx] = bf16_bits(wv_w[(size_t)k * 128 + n]);
    }
}

// ------------------------- CSR slot assignment -------------------------
__global__ void k_zero(int* cnt, int* fill, int n) {
    int i = blockIdx.x * blockDim.x + threadIdx.x;
    int stride = gridDim.x * blockDim.x;
    for (; i < n; i += stride) { cnt[i] = 0; fill[i] = 0; }
}

__global__ void k_count(const int* __restrict__ edst, int* cnt, int E) {
    int e = blockIdx.x * 256 + threadIdx.x;
    if (e < E) atomicAdd(&cnt[edst[e]], 1);
}

__global__ void k_scan1(const int* __restrict__ cnt, int* rs, int* bsum, int n) {
    __shared__ int s[256];
    int t = threadIdx.x;
    int i = blockIdx.x * 256 + t;
    int v = (i < n) ? cnt[i] : 0;
    s[t] = v;
    __syncthreads();
    for (int off = 1; off < 256; off <<= 1) {
        int x = (t >= off) ? s[t - off] : 0;
        __syncthreads();
        s[t] += x;
        __syncthreads();
    }
    if (i < n) rs[i] = s[t] - v;
    if (t == 255) bsum[blockIdx.x] = s[255];
}

__global__ void k_scan2(int* bsum, int nblk) {
    __shared__ int s[256];
    int t = threadIdx.x;
    int v = (t < nblk) ? bsum[t] : 0;
    s[t] = v;
    __syncthreads();
    for (int off = 1; off < 256; off <<= 1) {
        int x = (t >= off) ? s[t - off] : 0;
        __syncthreads();
        s[t] += x;
        __syncthreads();
    }
    if (t < nblk) bsum[t] = s[t] - v;
}

__global__ void k_scan3(int* rs, const int* __restrict__ bsum, int n) {
    int i = blockIdx.x * 256 + threadIdx.x;
    if (i < n) rs[i] += bsum[blockIdx.x];
}

__global__ void k_scatter(const int* __restrict__ edst, const int* __restrict__ rs,
                          int* fill, int* epos, int E) {
    int e = blockIdx.x * 256 + threadIdx.x;
    if (e < E) {
        int d = edst[e];
        epos[e] = rs[d] + atomicAdd(&fill[d], 1);
    }
}

// ------------------------- Q projection -------------------------
__global__ __launch_bounds__(256) void k_q(
    float* __restrict__ Q, const float* __restrict__ h,
    const float* __restrict__ wq_w, const float* __restrict__ qbias, int ndst)
{
    __shared__ float As[64 * 128];
    int row0 = blockIdx.x * 64;
    int tid = threadIdx.x;
    for (int idx = tid; idx < 64 * 128; idx += 256) {
        int r = idx >> 7, c = idx & 127;
        int gr = row0 + r;
        As[idx] = (gr < ndst) ? h[(size_t)gr * 128 + c] : 0.f;
    }
    __syncthreads();
    int cg = tid & 31, rg = tid >> 5;
    int c0 = cg * 4;
    float acc[8][4];
    #pragma unroll
    for (int i = 0; i < 8; ++i) { acc[i][0]=0.f; acc[i][1]=0.f; acc[i][2]=0.f; acc[i][3]=0.f; }
    for (int k = 0; k < 128; k += 4) {
        float4 w0 = *reinterpret_cast<const float4*>(wq_w + (size_t)(k+0)*128 + c0);
        float4 w1 = *reinterpret_cast<const float4*>(wq_w + (size_t)(k+1)*128 + c0);
        float4 w2 = *reinterpret_cast<const float4*>(wq_w + (size_t)(k+2)*128 + c0);
        float4 w3 = *reinterpret_cast<const float4*>(wq_w + (size_t)(k+3)*128 + c0);
        #pragma unroll
        for (int i = 0; i < 8; ++i) {
            float4 a = *reinterpret_cast<const float4*>(&As[(rg*8+i)*128 + k]);
            acc[i][0] = fmaf(a.x,w0.x,fmaf(a.y,w1.x,fmaf(a.z,w2.x,fmaf(a.w,w3.x,acc[i][0]))));
            acc[i][1] = fmaf(a.x,w0.y,fmaf(a.y,w1.y,fmaf(a.z,w2.y,fmaf(a.w,w3.y,acc[i][1]))));
            acc[i][2] = fmaf(a.x,w0.z,fmaf(a.y,w1.z,fmaf(a.z,w2.z,fmaf(a.w,w3.z,acc[i][2]))));
            acc[i][3] = fmaf(a.x,w0.w,fmaf(a.y,w1.w,fmaf(a.z,w2.w,fmaf(a.w,w3.w,acc[i][3]))));
        }
    }
    float q0 = qbias[c0], q1 = qbias[c0+1], q2 = qbias[c0+2], q3 = qbias[c0+3];
    #pragma unroll
    for (int i = 0; i < 8; ++i) {
        int r = row0 + rg*8 + i;
        if (r < ndst) {
            float4 o = make_float4(acc[i][0]+q0, acc[i][1]+q1, acc[i][2]+q2, acc[i][3]+q3);
            *reinterpret_cast<float4*>(Q + (size_t)r*128 + c0) = o;
        }
    }
}

// ------------------------- edge pass: MFMA K/V, write V rows + att -------------------------
// Wave handles 16 edges. V row stored bf16 at Vbuf[epos[e]] in col-permuted
// order (storage pos p = l15*8 + nt, col = nt*16 + l15) -> one 16B store/lane/row.
__global__ __launch_bounds__(256) void k_kvA(
    const float* __restrict__ h, const int* __restrict__ nbr, const int* __restrict__ edst,
    const float* __restrict__ dt, const float* __restrict__ ef,
    const float* __restrict__ time_w, const float* __restrict__ time_b,
    const unsigned short* __restrict__ wkT, const unsigned short* __restrict__ wvT,
    const float* __restrict__ wk_b, const float* __restrict__ Q,
    const int* __restrict__ epos,
    unsigned short* __restrict__ Vbuf, float2* __restrict__ att2, int ndst, int E)
{
    int tid  = threadIdx.x;
    int lane = tid & 63;
    int l15  = lane & 15;
    int lk   = lane >> 4;
    int e0   = blockIdx.x * 64 + (tid >> 6) * 16;

    // A-row identity
    int  ea = e0 + l15;
    bool va = ea < E;
    int  na = va ? nbr[ea] : 0;
    float da = va ? dt[ea] : 0.f;
    const float* hrow = h + (size_t)(ndst + na) * 128;
    const float* erow = ef + (size_t)ea * 64;

    // D-row identities
    int dstr[4], pe[4];
    bool evv[4];
    #pragma unroll
    for (int j = 0; j < 4; ++j) {
        int ed = e0 + lk * 4 + j;
        evv[j]  = ed < E;
        dstr[j] = evv[j] ? edst[ed] : 0;
        pe[j]   = evv[j] ? epos[ed] : 0;
    }

    // A fragments
    frag_u a[8];
    #pragma unroll
    for (int kk = 0; kk < 8; ++kk) {
        int c0 = kk * 32 + lk * 8;
        if (kk < 4) {
            float4 x = va ? *reinterpret_cast<const float4*>(hrow + c0)
                          : make_float4(0.f,0.f,0.f,0.f);
            float4 y = va ? *reinterpret_cast<const float4*>(hrow + c0 + 4)
                          : make_float4(0.f,0.f,0.f,0.f);
            a[kk].u[0] = pk2(x.x, x.y); a[kk].u[1] = pk2(x.z, x.w);
            a[kk].u[2] = pk2(y.x, y.y); a[kk].u[3] = pk2(y.z, y.w);
        } else if (kk < 6) {
            int c = c0 - 128;
            float4 x = va ? *reinterpret_cast<const float4*>(erow + c)
                          : make_float4(0.f,0.f,0.f,0.f);
            float4 y = va ? *reinterpret_cast<const float4*>(erow + c + 4)
                          : make_float4(0.f,0.f,0.f,0.f);
            a[kk].u[0] = pk2(x.x, x.y); a[kk].u[1] = pk2(x.z, x.w);
            a[kk].u[2] = pk2(y.x, y.y); a[kk].u[3] = pk2(y.z, y.w);
        } else {
            int j0 = c0 - 192;
            float v[8];
            #pragma unroll
            for (int t = 0; t < 8; ++t)
                v[t] = __cosf(fmaf(da, time_w[j0 + t], time_b[j0 + t]));
            a[kk].u[0] = pk2(v[0], v[1]); a[kk].u[1] = pk2(v[2], v[3]);
            a[kk].u[2] = pk2(v[4], v[5]); a[kk].u[3] = pk2(v[6], v[7]);
        }
    }

    // Q gather: qg[nt][j] = Q[dstr[j], nt*16+l15]
    float qg[8][4];
    #pragma unroll
    for (int nt = 0; nt < 8; ++nt) {
        int gc = nt * 16 + l15;
        #pragma unroll
        for (int j = 0; j < 4; ++j)
            qg[nt][j] = Q[(size_t)dstr[j] * 128 + gc];
    }

    // K GEMM
    f32x4 ck[8];
    #pragma unroll
    for (int nt = 0; nt < 8; ++nt) ck[nt] = (f32x4){0.f, 0.f, 0.f, 0.f};
    #pragma unroll
    for (int kk = 0; kk < 8; ++kk)
        #pragma unroll
        for (int nt = 0; nt < 8; ++nt) {
            short8 b = *reinterpret_cast<const short8*>(
                wkT + (size_t)(nt * 16 + l15) * 256 + kk * 32 + lk * 8);
            ck[nt] = __builtin_amdgcn_mfma_f32_16x16x32_bf16(a[kk].s, b, ck[nt], 0, 0, 0);
        }

    // att dot per head + 16-lane reduce, leaky
    float p0[4], p1[4];
    #pragma unroll
    for (int j = 0; j < 4; ++j) { p0[j] = 0.f; p1[j] = 0.f; }
    #pragma unroll
    for (int nt = 0; nt < 8; ++nt) {
        float kb = wk_b[nt * 16 + l15];
        #pragma unroll
        for (int j = 0; j < 4; ++j) {
            float t = (ck[nt][j] + kb) * qg[nt][j];
            if (nt < 4) p0[j] += t; else p1[j] += t;
        }
    }
    #pragma unroll
    for (int m = 1; m <= 8; m <<= 1)
        #pragma unroll
        for (int j = 0; j < 4; ++j) {
            p0[j] += __shfl_xor(p0[j], m, 64);
            p1[j] += __shfl_xor(p1[j], m, 64);
        }
    if (l15 == 0) {
        #pragma unroll
        for (int j = 0; j < 4; ++j)
            if (evv[j]) {
                float r0 = p0[j]; r0 = (r0 >= 0.f) ? r0 : 0.2f * r0;
                float r1 = p1[j]; r1 = (r1 >= 0.f) ? r1 : 0.2f * r1;
                att2[pe[j]] = make_float2(r0, r1);
            }
    }

    // V GEMM (reuses a[]; ck registers recycled by compiler)
    f32x4 cv[8];
    #pragma unroll
    for (int nt = 0; nt < 8; ++nt) cv[nt] = (f32x4){0.f, 0.f, 0.f, 0.f};
    #pragma unroll
    for (int kk = 0; kk < 8; ++kk)
        #pragma unroll
        for (int nt = 0; nt < 8; ++nt) {
            short8 b = *reinterpret_cast<const short8*>(
                wvT + (size_t)(nt * 16 + l15) * 256 + kk * 32 + lk * 8);
            cv[nt] = __builtin_amdgcn_mfma_f32_16x16x32_bf16(a[kk].s, b, cv[nt], 0, 0, 0);
        }

    // store raw V rows (vb folded later), col-permuted: pos = l15*8 + nt
    #pragma unroll
    for (int j = 0; j < 4; ++j)
        if (evv[j]) {
            uint4 val;
            val.x = pk2(cv[0][j], cv[1][j]);
            val.y = pk2(cv[2][j], cv[3][j]);
            val.z = pk2(cv[4][j], cv[5][j]);
            val.w = pk2(cv[6][j], cv[7][j]);
            *reinterpret_cast<uint4*>(Vbuf + (size_t)pe[j] * 128 + l15 * 8) = val;
        }
}

// ------------------------- streaming segment reduction -------------------------
// Wave per dst; rows rs[d]..rs[d]+cnt[d] are contiguous. Lane owns storage
// positions p0=2*lane, p1=p0+1 (cols (p&7)*16+(p>>3)).
__global__ __launch_bounds__(256) void k_agg(
    const unsigned short* __restrict__ Vbuf, const float2* __restrict__ att2,
    const int* __restrict__ rs, const int* __restrict__ cnt,
    const float* __restrict__ wv_b, float* __restrict__ agg, int ndst)
{
    int w = threadIdx.x >> 6, lane = threadIdx.x & 63;
    int d = blockIdx.x * 4 + w;
    if (d >= ndst) return;
    int p0 = lane * 2, p1 = p0 + 1;
    int c0 = ((p0 & 7) << 4) + (p0 >> 3);
    int c1 = ((p1 & 7) << 4) + (p1 >> 3);
    bool h0 = (p0 & 4) != 0, h1 = (p1 & 4) != 0;
    int base = rs[d], n = cnt[d];
    const unsigned* V32 = reinterpret_cast<const unsigned*>(Vbuf);
    float den0 = 0.f, den1 = 0.f, acc0 = 0.f, acc1 = 0.f;
    for (int i = 0; i < n; ++i) {
        size_t row = (size_t)(base + i);
        float2 at = att2[row];
        float ex0 = __expf(at.x), ex1 = __expf(at.y);
        den0 += ex0; den1 += ex1;
        unsigned vv = V32[row * 64 + lane];
        acc0 = fmaf(h0 ? ex1 : ex0, bflo(vv), acc0);
        acc1 = fmaf(h1 ? ex1 : ex0, bfhi(vv), acc1);
    }
    float o0 = 0.f, o1 = 0.f;
    if (n > 0) {
        o0 = acc0 / (h0 ? den1 : den0) + wv_b[c0];
        o1 = acc1 / (h1 ? den1 : den0) + wv_b[c1];
    }
    agg[(size_t)d * 128 + c0] = o0;
    agg[(size_t)d * 128 + c1] = o1;
}

// ------------------------- output: GEMM + ReLU + LayerNorm -------------------------
__global__ __launch_bounds__(256) void k_out(
    const float* __restrict__ agg,
    const float* __restrict__ h, const float* __restrict__ wo_w, const float* __restrict__ wo_b,
    const float* __restrict__ ln_g, const float* __restrict__ ln_b,
    float* __restrict__ out, int ndst)
{
    __shared__ float As[64 * 256];
    int row0 = blockIdx.x * 64;
    int tid = threadIdx.x;
    for (int idx = tid; idx < 64 * 256; idx += 256) {
        int r = idx >> 8, c = idx & 255;
        int gr = row0 + r;
        float v = 0.f;
        if (gr < ndst)
            v = (c < 128) ? agg[(size_t)gr * 128 + c] : h[(size_t)gr * 128 + (c - 128)];
        As[idx] = v;
    }
    __syncthreads();
    int cg = tid & 31, rg = tid >> 5;
    int c0 = cg * 4;
    float acc[8][4];
    #pragma unroll
    for (int i = 0; i < 8; ++i) { acc[i][0]=0.f; acc[i][1]=0.f; acc[i][2]=0.f; acc[i][3]=0.f; }
    for (int k = 0; k < 256; k += 4) {
        float4 w0 = *reinterpret_cast<const float4*>(wo_w + (size_t)(k+0)*128 + c0);
        float4 w1 = *reinterpret_cast<const float4*>(wo_w + (size_t)(k+1)*128 + c0);
        float4 w2 = *reinterpret_cast<const float4*>(wo_w + (size_t)(k+2)*128 + c0);
        float4 w3 = *reinterpret_cast<const float4*>(wo_w + (size_t)(k+3)*128 + c0);
        #pragma unroll
        for (int i = 0; i < 8; ++i) {
            float4 a = *reinterpret_cast<const float4*>(&As[(rg*8+i)*256 + k]);
            acc[i][0] = fmaf(a.x,w0.x,fmaf(a.y,w1.x,fmaf(a.z,w2.x,fmaf(a.w,w3.x,acc[i][0]))));
            acc[i][1] = fmaf(a.x,w0.y,fmaf(a.y,w1.y,fmaf(a.z,w2.y,fmaf(a.w,w3.y,acc[i][1]))));
            acc[i][2] = fmaf(a.x,w0.z,fmaf(a.y,w1.z,fmaf(a.z,w2.z,fmaf(a.w,w3.z,acc[i][2]))));
            acc[i][3] = fmaf(a.x,w0.w,fmaf(a.y,w1.w,fmaf(a.z,w2.w,fmaf(a.w,w3.w,acc[i][3]))));
        }
    }
    float b0 = wo_b[c0], b1 = wo_b[c0+1], b2 = wo_b[c0+2], b3 = wo_b[c0+3];
    float g0 = ln_g[c0], g1 = ln_g[c0+1], g2 = ln_g[c0+2], g3 = ln_g[c0+3];
    float l0 = ln_b[c0], l1 = ln_b[c0+1], l2 = ln_b[c0+2], l3 = ln_b[c0+3];
    #pragma unroll
    for (int i = 0; i < 8; ++i) {
        float x0 = fmaxf(acc[i][0] + b0, 0.f);
        float x1 = fmaxf(acc[i][1] + b1, 0.f);
        float x2 = fmaxf(acc[i][2] + b2, 0.f);
        float x3 = fmaxf(acc[i][3] + b3, 0.f);
        float s1 = x0 + x1 + x2 + x3;
        float s2 = x0*x0 + x1*x1 + x2*x2 + x3*x3;
        #pragma unroll
        for (int mm = 1; mm <= 16; mm <<= 1) {
            s1 += __shfl_xor(s1, mm, 64);
            s2 += __shfl_xor(s2, mm, 64);
        }
        float mean = s1 * (1.f / 128.f);
        float var  = s2 * (1.f / 128.f) - mean * mean;
        float rstd = rsqrtf(var + 1e-5f);
        int r = row0 + rg * 8 + i;
        if (r < ndst) {
            float4 o = make_float4((x0 - mean) * rstd * g0 + l0,
                                   (x1 - mean) * rstd * g1 + l1,
                                   (x2 - mean) * rstd * g2 + l2,
                                   (x3 - mean) * rstd * g3 + l3);
            *reinterpret_cast<float4*>(out + (size_t)r * 128 + c0) = o;
        }
    }
}

extern "C" void kernel_launch(void* const* d_in, const int* in_sizes, int n_in,
                              void* d_out, int out_size, void* d_ws, size_t ws_size,
                              hipStream_t stream) {
    const float* h      = (const float*)d_in[0];
    const float* dt     = (const float*)d_in[1];
    const float* ef     = (const float*)d_in[2];
    const float* time_w = (const float*)d_in[3];
    const float* time_b = (const float*)d_in[4];
    const float* wq_w   = (const float*)d_in[5];
    const float* wq_b   = (const float*)d_in[6];
    const float* wk_w   = (const float*)d_in[7];
    const float* wk_b   = (const float*)d_in[8];
    const float* wv_w   = (const float*)d_in[9];
    const float* wv_b   = (const float*)d_in[10];
    const float* wo_w   = (const float*)d_in[11];
    const float* wo_b   = (const float*)d_in[12];
    const float* ln_g   = (const float*)d_in[13];
    const float* ln_b   = (const float*)d_in[14];
    const int* nbr      = (const int*)d_in[15];
    const int* edst     = (const int*)d_in[16];

    int E    = in_sizes[1];
    int ndst = out_size / 128;
    int nblk = (ndst + 255) / 256;

    char* wsb = (char*)d_ws;
    float* qbias = (float*)wsb;                 wsb += 512;
    float* Q     = (float*)wsb;                 wsb += (size_t)ndst * 128 * 4;
    float* agg   = (float*)wsb;                 wsb += (size_t)ndst * 128 * 4;
    unsigned short* wkT = (unsigned short*)wsb; wsb += 32768 * 2;
    unsigned short* wvT = (unsigned short*)wsb; wsb += 32768 * 2;
    int* cnt    = (int*)wsb;                    wsb += (size_t)ndst * 4;
    int* rs     = (int*)wsb;                    wsb += (size_t)ndst * 4;
    int* fill   = (int*)wsb;                    wsb += (size_t)ndst * 4;
    int* bsum   = (int*)wsb;                    wsb += 1024;
    int* epos   = (int*)wsb;                    wsb += (size_t)E * 4;
    float2* att2 = (float2*)wsb;                wsb += (size_t)E * 8;
    unsigned short* Vbuf = (unsigned short*)wsb; wsb += (size_t)E * 128 * 2;
    // total ~= 52 + 1 + 2 + 64 MB ~= 120 MB

    k_zero<<<256, 256, 0, stream>>>(cnt, fill, ndst);
    k_prep<<<1, 128, 0, stream>>>(qbias, wq_w, wq_b, time_b);
    k_pack<<<128, 256, 0, stream>>>(wkT, wvT, wk_w, wv_w);
    k_count<<<(E + 255) / 256, 256, 0, stream>>>(edst, cnt, E);
    k_scan1<<<nblk, 256, 0, stream>>>(cnt, rs, bsum, ndst);
    k_scan2<<<1, 256, 0, stream>>>(bsum, nblk);
    k_scan3<<<nblk, 256, 0, stream>>>(rs, bsum, ndst);
    k_scatter<<<(E + 255) / 256, 256, 0, stream>>>(edst, rs, fill, epos, E);
    k_q<<<(ndst + 63) / 64, 256, 0, stream>>>(Q, h, wq_w, qbias, ndst);
    k_kvA<<<(E + 63) / 64, 256, 0, stream>>>(h, nbr, edst, dt, ef, time_w, time_b,
                                             wkT, wvT, wk_b, Q, epos, Vbuf, att2, ndst, E);
    k_agg<<<(ndst + 3) / 4, 256, 0, stream>>>(Vbuf, att2, rs, cnt, wv_b, agg, ndst);
    k_out<<<(ndst + 63) / 64, 256, 0, stream>>>(agg, h, wo_w, wo_b, ln_g, ln_b,
                                                (float*)d_out, ndst);
}

// Round 8
// 509.270 us; speedup vs baseline: 2.3716x; 1.0118x over previous
//
#include <hip/hip_runtime.h>
#include <hip/hip_bf16.h>
#include <math.h>

// TemporalTransformerConv (TGAT-like) for MI355X — round 8.
// Same pipeline as round 7; k_kvA inner loops restructured to batch B-operand
// loads (8 independent loads -> 1 waitcnt -> 8 MFMAs) instead of load->mfma
// interleave that serialized at ~650 cy/load. A/Q loads hoisted, V-B kk=0
// prefetched under the att shuffle section.

using bf16 = __hip_bfloat16;
typedef __attribute__((ext_vector_type(8))) short short8;
typedef __attribute__((ext_vector_type(4))) float f32x4;

static __device__ __forceinline__ unsigned short bf16_bits(float x) {
    bf16 h = __float2bfloat16(x);
    unsigned short b;
    __builtin_memcpy(&b, &h, 2);
    return b;
}
static __device__ __forceinline__ unsigned pk2(float x, float y) {
    return (unsigned)bf16_bits(x) | ((unsigned)bf16_bits(y) << 16);
}
static __device__ __forceinline__ float bflo(unsigned u) {
    return __uint_as_float(u << 16);
}
static __device__ __forceinline__ float bfhi(unsigned u) {
    return __uint_as_float(u & 0xffff0000u);
}
union frag_u { short8 s; unsigned u[4]; };

// ------------------------- prep -------------------------
__global__ void k_prep(float* qbias, const float* __restrict__ wq_w,
                       const float* __restrict__ wq_b, const float* __restrict__ time_b) {
    int c = threadIdx.x;
    if (c < 128) {
        float s = wq_b[c];
        for (int j = 0; j < 64; ++j)
            s += cosf(time_b[j]) * wq_w[(128 + j) * 128 + c];
        qbias[c] = s;
    }
}

__global__ void k_pack(unsigned short* wkT, unsigned short* wvT,
                       const float* __restrict__ wk_w, const float* __restrict__ wv_w) {
    int idx = blockIdx.x * blockDim.x + threadIdx.x;  // 32768
    if (idx < 32768) {
        int n = idx >> 8, k = idx & 255;
        wkT[idx] = bf16_bits(wk_w[(size_t)k * 128 + n]);
        wvT[idx] = bf16_bits(wv_w[(size_t)k * 128 + n]);
    }
}

// ------------------------- CSR slot assignment -------------------------
__global__ void k_zero(int* cnt, int* fill, int n) {
    int i = blockIdx.x * blockDim.x + threadIdx.x;
    int stride = gridDim.x * blockDim.x;
    for (; i < n; i += stride) { cnt[i] = 0; fill[i] = 0; }
}

__global__ void k_count(const int* __restrict__ edst, int* cnt, int E) {
    int e = blockIdx.x * 256 + threadIdx.x;
    if (e < E) atomicAdd(&cnt[edst[e]], 1);
}

__global__ void k_scan1(const int* __restrict__ cnt, int* rs, int* bsum, int n) {
    __shared__ int s[256];
    int t = threadIdx.x;
    int i = blockIdx.x * 256 + t;
    int v = (i < n) ? cnt[i] : 0;
    s[t] = v;
    __syncthreads();
    for (int off = 1; off < 256; off <<= 1) {
        int x = (t >= off) ? s[t - off] : 0;
        __syncthreads();
        s[t] += x;
        __syncthreads();
    }
    if (i < n) rs[i] = s[t] - v;
    if (t == 255) bsum[blockIdx.x] = s[255];
}

__global__ void k_scan2(int* bsum, int nblk) {
    __shared__ int s[256];
    int t = threadIdx.x;
    int v = (t < nblk) ? bsum[t] : 0;
    s[t] = v;
    __syncthreads();
    for (int off = 1; off < 256; off <<= 1) {
        int x = (t >= off) ? s[t - off] : 0;
        __syncthreads();
        s[t] += x;
        __syncthreads();
    }
    if (t < nblk) bsum[t] = s[t] - v;
}

__global__ void k_scan3(int* rs, const int* __restrict__ bsum, int n) {
    int i = blockIdx.x * 256 + threadIdx.x;
    if (i < n) rs[i] += bsum[blockIdx.x];
}

__global__ void k_scatter(const int* __restrict__ edst, const int* __restrict__ rs,
                          int* fill, int* epos, int E) {
    int e = blockIdx.x * 256 + threadIdx.x;
    if (e < E) {
        int d = edst[e];
        epos[e] = rs[d] + atomicAdd(&fill[d], 1);
    }
}

// ------------------------- Q projection -------------------------
__global__ __launch_bounds__(256) void k_q(
    float* __restrict__ Q, const float* __restrict__ h,
    const float* __restrict__ wq_w, const float* __restrict__ qbias, int ndst)
{
    __shared__ float As[64 * 128];
    int row0 = blockIdx.x * 64;
    int tid = threadIdx.x;
    for (int idx = tid; idx < 64 * 128; idx += 256) {
        int r = idx >> 7, c = idx & 127;
        int gr = row0 + r;
        As[idx] = (gr < ndst) ? h[(size_t)gr * 128 + c] : 0.f;
    }
    __syncthreads();
    int cg = tid & 31, rg = tid >> 5;
    int c0 = cg * 4;
    float acc[8][4];
    #pragma unroll
    for (int i = 0; i < 8; ++i) { acc[i][0]=0.f; acc[i][1]=0.f; acc[i][2]=0.f; acc[i][3]=0.f; }
    for (int k = 0; k < 128; k += 4) {
        float4 w0 = *reinterpret_cast<const float4*>(wq_w + (size_t)(k+0)*128 + c0);
        float4 w1 = *reinterpret_cast<const float4*>(wq_w + (size_t)(k+1)*128 + c0);
        float4 w2 = *reinterpret_cast<const float4*>(wq_w + (size_t)(k+2)*128 + c0);
        float4 w3 = *reinterpret_cast<const float4*>(wq_w + (size_t)(k+3)*128 + c0);
        #pragma unroll
        for (int i = 0; i < 8; ++i) {
            float4 a = *reinterpret_cast<const float4*>(&As[(rg*8+i)*128 + k]);
            acc[i][0] = fmaf(a.x,w0.x,fmaf(a.y,w1.x,fmaf(a.z,w2.x,fmaf(a.w,w3.x,acc[i][0]))));
            acc[i][1] = fmaf(a.x,w0.y,fmaf(a.y,w1.y,fmaf(a.z,w2.y,fmaf(a.w,w3.y,acc[i][1]))));
            acc[i][2] = fmaf(a.x,w0.z,fmaf(a.y,w1.z,fmaf(a.z,w2.z,fmaf(a.w,w3.z,acc[i][2]))));
            acc[i][3] = fmaf(a.x,w0.w,fmaf(a.y,w1.w,fmaf(a.z,w2.w,fmaf(a.w,w3.w,acc[i][3]))));
        }
    }
    float q0 = qbias[c0], q1 = qbias[c0+1], q2 = qbias[c0+2], q3 = qbias[c0+3];
    #pragma unroll
    for (int i = 0; i < 8; ++i) {
        int r = row0 + rg*8 + i;
        if (r < ndst) {
            float4 o = make_float4(acc[i][0]+q0, acc[i][1]+q1, acc[i][2]+q2, acc[i][3]+q3);
            *reinterpret_cast<float4*>(Q + (size_t)r*128 + c0) = o;
        }
    }
}

// ------------------------- edge pass (batched-load MFMA) -------------------------
__global__ __launch_bounds__(256) void k_kvA(
    const float* __restrict__ h, const int* __restrict__ nbr, const int* __restrict__ edst,
    const float* __restrict__ dt, const float* __restrict__ ef,
    const float* __restrict__ time_w, const float* __restrict__ time_b,
    const unsigned short* __restrict__ wkT, const unsigned short* __restrict__ wvT,
    const float* __restrict__ wk_b, const float* __restrict__ Q,
    const int* __restrict__ epos,
    unsigned short* __restrict__ Vbuf, float2* __restrict__ att2, int ndst, int E)
{
    int tid  = threadIdx.x;
    int lane = tid & 63;
    int l15  = lane & 15;
    int lk   = lane >> 4;
    int e0   = blockIdx.x * 64 + (tid >> 6) * 16;

    // identities
    int  ea = e0 + l15;
    bool va = ea < E;
    int  na = va ? nbr[ea] : 0;
    float da = va ? dt[ea] : 0.f;
    const float* hrow = h + (size_t)(ndst + na) * 128;
    const float* erow = ef + (size_t)ea * 64;

    int dstr[4], pe[4];
    bool evv[4];
    #pragma unroll
    for (int j = 0; j < 4; ++j) {
        int ed = e0 + lk * 4 + j;
        evv[j]  = ed < E;
        dstr[j] = evv[j] ? edst[ed] : 0;
        pe[j]   = evv[j] ? epos[ed] : 0;
    }

    // ---- issue all A-region vector loads (12 independent) ----
    float4 hx[4][2], ex_[2][2];
    const float4 z4 = make_float4(0.f, 0.f, 0.f, 0.f);
    #pragma unroll
    for (int kk = 0; kk < 4; ++kk) {
        int c0 = kk * 32 + lk * 8;
        hx[kk][0] = va ? *reinterpret_cast<const float4*>(hrow + c0)     : z4;
        hx[kk][1] = va ? *reinterpret_cast<const float4*>(hrow + c0 + 4) : z4;
    }
    #pragma unroll
    for (int t = 0; t < 2; ++t) {
        int c = (4 + t) * 32 + lk * 8 - 128;
        ex_[t][0] = va ? *reinterpret_cast<const float4*>(erow + c)     : z4;
        ex_[t][1] = va ? *reinterpret_cast<const float4*>(erow + c + 4) : z4;
    }

    // ---- issue Q gather (32 independent scalar loads) ----
    float qg[8][4];
    #pragma unroll
    for (int nt = 0; nt < 8; ++nt) {
        int gc = nt * 16 + l15;
        #pragma unroll
        for (int j = 0; j < 4; ++j)
            qg[nt][j] = Q[(size_t)dstr[j] * 128 + gc];
    }

    // ---- VALU while loads fly: time-feature cos ----
    float tf[16];
    {
        int j0 = lk * 8;  // kk=6 -> cols 192+lk*8 -> time idx lk*8; kk=7 -> +32
        #pragma unroll
        for (int t = 0; t < 8; ++t) tf[t]     = __cosf(fmaf(da, time_w[j0 + t],      time_b[j0 + t]));
        #pragma unroll
        for (int t = 0; t < 8; ++t) tf[8 + t] = __cosf(fmaf(da, time_w[j0 + 32 + t], time_b[j0 + 32 + t]));
    }

    // ---- pack A fragments ----
    frag_u a[8];
    #pragma unroll
    for (int kk = 0; kk < 4; ++kk) {
        a[kk].u[0] = pk2(hx[kk][0].x, hx[kk][0].y); a[kk].u[1] = pk2(hx[kk][0].z, hx[kk][0].w);
        a[kk].u[2] = pk2(hx[kk][1].x, hx[kk][1].y); a[kk].u[3] = pk2(hx[kk][1].z, hx[kk][1].w);
    }
    #pragma unroll
    for (int t = 0; t < 2; ++t) {
        a[4+t].u[0] = pk2(ex_[t][0].x, ex_[t][0].y); a[4+t].u[1] = pk2(ex_[t][0].z, ex_[t][0].w);
        a[4+t].u[2] = pk2(ex_[t][1].x, ex_[t][1].y); a[4+t].u[3] = pk2(ex_[t][1].z, ex_[t][1].w);
    }
    a[6].u[0] = pk2(tf[0], tf[1]);  a[6].u[1] = pk2(tf[2], tf[3]);
    a[6].u[2] = pk2(tf[4], tf[5]);  a[6].u[3] = pk2(tf[6], tf[7]);
    a[7].u[0] = pk2(tf[8], tf[9]);  a[7].u[1] = pk2(tf[10], tf[11]);
    a[7].u[2] = pk2(tf[12], tf[13]); a[7].u[3] = pk2(tf[14], tf[15]);

    // ---- K GEMM: per kk, 8 batched B loads then 8 MFMAs ----
    const size_t ntstride = 16 * 256;  // B row-group stride in elements
    f32x4 ck[8];
    #pragma unroll
    for (int nt = 0; nt < 8; ++nt) ck[nt] = (f32x4){0.f, 0.f, 0.f, 0.f};
    #pragma unroll
    for (int kk = 0; kk < 8; ++kk) {
        const unsigned short* bp = wkT + (size_t)l15 * 256 + kk * 32 + lk * 8;
        short8 b0 = *reinterpret_cast<const short8*>(bp + 0 * ntstride);
        short8 b1 = *reinterpret_cast<const short8*>(bp + 1 * ntstride);
        short8 b2 = *reinterpret_cast<const short8*>(bp + 2 * ntstride);
        short8 b3 = *reinterpret_cast<const short8*>(bp + 3 * ntstride);
        short8 b4 = *reinterpret_cast<const short8*>(bp + 4 * ntstride);
        short8 b5 = *reinterpret_cast<const short8*>(bp + 5 * ntstride);
        short8 b6 = *reinterpret_cast<const short8*>(bp + 6 * ntstride);
        short8 b7 = *reinterpret_cast<const short8*>(bp + 7 * ntstride);
        ck[0] = __builtin_amdgcn_mfma_f32_16x16x32_bf16(a[kk].s, b0, ck[0], 0, 0, 0);
        ck[1] = __builtin_amdgcn_mfma_f32_16x16x32_bf16(a[kk].s, b1, ck[1], 0, 0, 0);
        ck[2] = __builtin_amdgcn_mfma_f32_16x16x32_bf16(a[kk].s, b2, ck[2], 0, 0, 0);
        ck[3] = __builtin_amdgcn_mfma_f32_16x16x32_bf16(a[kk].s, b3, ck[3], 0, 0, 0);
        ck[4] = __builtin_amdgcn_mfma_f32_16x16x32_bf16(a[kk].s, b4, ck[4], 0, 0, 0);
        ck[5] = __builtin_amdgcn_mfma_f32_16x16x32_bf16(a[kk].s, b5, ck[5], 0, 0, 0);
        ck[6] = __builtin_amdgcn_mfma_f32_16x16x32_bf16(a[kk].s, b6, ck[6], 0, 0, 0);
        ck[7] = __builtin_amdgcn_mfma_f32_16x16x32_bf16(a[kk].s, b7, ck[7], 0, 0, 0);
    }

    // ---- prefetch V GEMM kk=0 B-fragments (in flight during att section) ----
    const unsigned short* vp0 = wvT + (size_t)l15 * 256 + lk * 8;
    short8 v0 = *reinterpret_cast<const short8*>(vp0 + 0 * ntstride);
    short8 v1 = *reinterpret_cast<const short8*>(vp0 + 1 * ntstride);
    short8 v2 = *reinterpret_cast<const short8*>(vp0 + 2 * ntstride);
    short8 v3 = *reinterpret_cast<const short8*>(vp0 + 3 * ntstride);
    short8 v4 = *reinterpret_cast<const short8*>(vp0 + 4 * ntstride);
    short8 v5 = *reinterpret_cast<const short8*>(vp0 + 5 * ntstride);
    short8 v6 = *reinterpret_cast<const short8*>(vp0 + 6 * ntstride);
    short8 v7 = *reinterpret_cast<const short8*>(vp0 + 7 * ntstride);

    // ---- att dot per head + 16-lane reduce, leaky, store ----
    float p0[4], p1[4];
    #pragma unroll
    for (int j = 0; j < 4; ++j) { p0[j] = 0.f; p1[j] = 0.f; }
    #pragma unroll
    for (int nt = 0; nt < 8; ++nt) {
        float kb = wk_b[nt * 16 + l15];
        #pragma unroll
        for (int j = 0; j < 4; ++j) {
            float t = (ck[nt][j] + kb) * qg[nt][j];
            if (nt < 4) p0[j] += t; else p1[j] += t;
        }
    }
    #pragma unroll
    for (int m = 1; m <= 8; m <<= 1)
        #pragma unroll
        for (int j = 0; j < 4; ++j) {
            p0[j] += __shfl_xor(p0[j], m, 64);
            p1[j] += __shfl_xor(p1[j], m, 64);
        }
    if (l15 == 0) {
        #pragma unroll
        for (int j = 0; j < 4; ++j)
            if (evv[j]) {
                float r0 = p0[j]; r0 = (r0 >= 0.f) ? r0 : 0.2f * r0;
                float r1 = p1[j]; r1 = (r1 >= 0.f) ? r1 : 0.2f * r1;
                att2[pe[j]] = make_float2(r0, r1);
            }
    }

    // ---- V GEMM: kk=0 from prefetch, kk=1..7 batched ----
    f32x4 cv[8];
    #pragma unroll
    for (int nt = 0; nt < 8; ++nt) cv[nt] = (f32x4){0.f, 0.f, 0.f, 0.f};
    cv[0] = __builtin_amdgcn_mfma_f32_16x16x32_bf16(a[0].s, v0, cv[0], 0, 0, 0);
    cv[1] = __builtin_amdgcn_mfma_f32_16x16x32_bf16(a[0].s, v1, cv[1], 0, 0, 0);
    cv[2] = __builtin_amdgcn_mfma_f32_16x16x32_bf16(a[0].s, v2, cv[2], 0, 0, 0);
    cv[3] = __builtin_amdgcn_mfma_f32_16x16x32_bf16(a[0].s, v3, cv[3], 0, 0, 0);
    cv[4] = __builtin_amdgcn_mfma_f32_16x16x32_bf16(a[0].s, v4, cv[4], 0, 0, 0);
    cv[5] = __builtin_amdgcn_mfma_f32_16x16x32_bf16(a[0].s, v5, cv[5], 0, 0, 0);
    cv[6] = __builtin_amdgcn_mfma_f32_16x16x32_bf16(a[0].s, v6, cv[6], 0, 0, 0);
    cv[7] = __builtin_amdgcn_mfma_f32_16x16x32_bf16(a[0].s, v7, cv[7], 0, 0, 0);
    #pragma unroll
    for (int kk = 1; kk < 8; ++kk) {
        const unsigned short* bp = wvT + (size_t)l15 * 256 + kk * 32 + lk * 8;
        short8 b0 = *reinterpret_cast<const short8*>(bp + 0 * ntstride);
        short8 b1 = *reinterpret_cast<const short8*>(bp + 1 * ntstride);
        short8 b2 = *reinterpret_cast<const short8*>(bp + 2 * ntstride);
        short8 b3 = *reinterpret_cast<const short8*>(bp + 3 * ntstride);
        short8 b4 = *reinterpret_cast<const short8*>(bp + 4 * ntstride);
        short8 b5 = *reinterpret_cast<const short8*>(bp + 5 * ntstride);
        short8 b6 = *reinterpret_cast<const short8*>(bp + 6 * ntstride);
        short8 b7 = *reinterpret_cast<const short8*>(bp + 7 * ntstride);
        cv[0] = __builtin_amdgcn_mfma_f32_16x16x32_bf16(a[kk].s, b0, cv[0], 0, 0, 0);
        cv[1] = __builtin_amdgcn_mfma_f32_16x16x32_bf16(a[kk].s, b1, cv[1], 0, 0, 0);
        cv[2] = __builtin_amdgcn_mfma_f32_16x16x32_bf16(a[kk].s, b2, cv[2], 0, 0, 0);
        cv[3] = __builtin_amdgcn_mfma_f32_16x16x32_bf16(a[kk].s, b3, cv[3], 0, 0, 0);
        cv[4] = __builtin_amdgcn_mfma_f32_16x16x32_bf16(a[kk].s, b4, cv[4], 0, 0, 0);
        cv[5] = __builtin_amdgcn_mfma_f32_16x16x32_bf16(a[kk].s, b5, cv[5], 0, 0, 0);
        cv[6] = __builtin_amdgcn_mfma_f32_16x16x32_bf16(a[kk].s, b6, cv[6], 0, 0, 0);
        cv[7] = __builtin_amdgcn_mfma_f32_16x16x32_bf16(a[kk].s, b7, cv[7], 0, 0, 0);
    }

    // ---- store raw V rows, col-permuted: pos = l15*8 + nt ----
    #pragma unroll
    for (int j = 0; j < 4; ++j)
        if (evv[j]) {
            uint4 val;
            val.x = pk2(cv[0][j], cv[1][j]);
            val.y = pk2(cv[2][j], cv[3][j]);
            val.z = pk2(cv[4][j], cv[5][j]);
            val.w = pk2(cv[6][j], cv[7][j]);
            *reinterpret_cast<uint4*>(Vbuf + (size_t)pe[j] * 128 + l15 * 8) = val;
        }
}

// ------------------------- streaming segment reduction -------------------------
__global__ __launch_bounds__(256) void k_agg(
    const unsigned short* __restrict__ Vbuf, const float2* __restrict__ att2,
    const int* __restrict__ rs, const int* __restrict__ cnt,
    const float* __restrict__ wv_b, float* __restrict__ agg, int ndst)
{
    int w = threadIdx.x >> 6, lane = threadIdx.x & 63;
    int d = blockIdx.x * 4 + w;
    if (d >= ndst) return;
    int p0 = lane * 2, p1 = p0 + 1;
    int c0 = ((p0 & 7) << 4) + (p0 >> 3);
    int c1 = ((p1 & 7) << 4) + (p1 >> 3);
    bool h0 = (p0 & 4) != 0, h1 = (p1 & 4) != 0;
    int base = rs[d], n = cnt[d];
    const unsigned* V32 = reinterpret_cast<const unsigned*>(Vbuf);
    float den0 = 0.f, den1 = 0.f, acc0 = 0.f, acc1 = 0.f;
    for (int i = 0; i < n; ++i) {
        size_t row = (size_t)(base + i);
        float2 at = att2[row];
        float ex0 = __expf(at.x), ex1 = __expf(at.y);
        den0 += ex0; den1 += ex1;
        unsigned vv = V32[row * 64 + lane];
        acc0 = fmaf(h0 ? ex1 : ex0, bflo(vv), acc0);
        acc1 = fmaf(h1 ? ex1 : ex0, bfhi(vv), acc1);
    }
    float o0 = 0.f, o1 = 0.f;
    if (n > 0) {
        o0 = acc0 / (h0 ? den1 : den0) + wv_b[c0];
        o1 = acc1 / (h1 ? den1 : den0) + wv_b[c1];
    }
    agg[(size_t)d * 128 + c0] = o0;
    agg[(size_t)d * 128 + c1] = o1;
}

// ------------------------- output: GEMM + ReLU + LayerNorm -------------------------
__global__ __launch_bounds__(256) void k_out(
    const float* __restrict__ agg,
    const float* __restrict__ h, const float* __restrict__ wo_w, const float* __restrict__ wo_b,
    const float* __restrict__ ln_g, const float* __restrict__ ln_b,
    float* __restrict__ out, int ndst)
{
    __shared__ float As[64 * 256];
    int row0 = blockIdx.x * 64;
    int tid = threadIdx.x;
    for (int idx = tid; idx < 64 * 256; idx += 256) {
        int r = idx >> 8, c = idx & 255;
        int gr = row0 + r;
        float v = 0.f;
        if (gr < ndst)
            v = (c < 128) ? agg[(size_t)gr * 128 + c] : h[(size_t)gr * 128 + (c - 128)];
        As[idx] = v;
    }
    __syncthreads();
    int cg = tid & 31, rg = tid >> 5;
    int c0 = cg * 4;
    float acc[8][4];
    #pragma unroll
    for (int i = 0; i < 8; ++i) { acc[i][0]=0.f; acc[i][1]=0.f; acc[i][2]=0.f; acc[i][3]=0.f; }
    for (int k = 0; k < 256; k += 4) {
        float4 w0 = *reinterpret_cast<const float4*>(wo_w + (size_t)(k+0)*128 + c0);
        float4 w1 = *reinterpret_cast<const float4*>(wo_w + (size_t)(k+1)*128 + c0);
        float4 w2 = *reinterpret_cast<const float4*>(wo_w + (size_t)(k+2)*128 + c0);
        float4 w3 = *reinterpret_cast<const float4*>(wo_w + (size_t)(k+3)*128 + c0);
        #pragma unroll
        for (int i = 0; i < 8; ++i) {
            float4 a = *reinterpret_cast<const float4*>(&As[(rg*8+i)*256 + k]);
            acc[i][0] = fmaf(a.x,w0.x,fmaf(a.y,w1.x,fmaf(a.z,w2.x,fmaf(a.w,w3.x,acc[i][0]))));
            acc[i][1] = fmaf(a.x,w0.y,fmaf(a.y,w1.y,fmaf(a.z,w2.y,fmaf(a.w,w3.y,acc[i][1]))));
            acc[i][2] = fmaf(a.x,w0.z,fmaf(a.y,w1.z,fmaf(a.z,w2.z,fmaf(a.w,w3.z,acc[i][2]))));
            acc[i][3] = fmaf(a.x,w0.w,fmaf(a.y,w1.w,fmaf(a.z,w2.w,fmaf(a.w,w3.w,acc[i][3]))));
        }
    }
    float b0 = wo_b[c0], b1 = wo_b[c0+1], b2 = wo_b[c0+2], b3 = wo_b[c0+3];
    float g0 = ln_g[c0], g1 = ln_g[c0+1], g2 = ln_g[c0+2], g3 = ln_g[c0+3];
    float l0 = ln_b[c0], l1 = ln_b[c0+1], l2 = ln_b[c0+2], l3 = ln_b[c0+3];
    #pragma unroll
    for (int i = 0; i < 8; ++i) {
        float x0 = fmaxf(acc[i][0] + b0, 0.f);
        float x1 = fmaxf(acc[i][1] + b1, 0.f);
        float x2 = fmaxf(acc[i][2] + b2, 0.f);
        float x3 = fmaxf(acc[i][3] + b3, 0.f);
        float s1 = x0 + x1 + x2 + x3;
        float s2 = x0*x0 + x1*x1 + x2*x2 + x3*x3;
        #pragma unroll
        for (int mm = 1; mm <= 16; mm <<= 1) {
            s1 += __shfl_xor(s1, mm, 64);
            s2 += __shfl_xor(s2, mm, 64);
        }
        float mean = s1 * (1.f / 128.f);
        float var  = s2 * (1.f / 128.f) - mean * mean;
        float rstd = rsqrtf(var + 1e-5f);
        int r = row0 + rg * 8 + i;
        if (r < ndst) {
            float4 o = make_float4((x0 - mean) * rstd * g0 + l0,
                                   (x1 - mean) * rstd * g1 + l1,
                                   (x2 - mean) * rstd * g2 + l2,
                                   (x3 - mean) * rstd * g3 + l3);
            *reinterpret_cast<float4*>(out + (size_t)r * 128 + c0) = o;
        }
    }
}

extern "C" void kernel_launch(void* const* d_in, const int* in_sizes, int n_in,
                              void* d_out, int out_size, void* d_ws, size_t ws_size,
                              hipStream_t stream) {
    const float* h      = (const float*)d_in[0];
    const float* dt     = (const float*)d_in[1];
    const float* ef     = (const float*)d_in[2];
    const float* time_w = (const float*)d_in[3];
    const float* time_b = (const float*)d_in[4];
    const float* wq_w   = (const float*)d_in[5];
    const float* wq_b   = (const float*)d_in[6];
    const float* wk_w   = (const float*)d_in[7];
    const float* wk_b   = (const float*)d_in[8];
    const float* wv_w   = (const float*)d_in[9];
    const float* wv_b   = (const float*)d_in[10];
    const float* wo_w   = (const float*)d_in[11];
    const float* wo_b   = (const float*)d_in[12];
    const float* ln_g   = (const float*)d_in[13];
    const float* ln_b   = (const float*)d_in[14];
    const int* nbr      = (const int*)d_in[15];
    const int* edst     = (const int*)d_in[16];

    int E    = in_sizes[1];
    int ndst = out_size / 128;
    int nblk = (ndst + 255) / 256;

    char* wsb = (char*)d_ws;
    float* qbias = (float*)wsb;                 wsb += 512;
    float* Q     = (float*)wsb;                 wsb += (size_t)ndst * 128 * 4;
    float* agg   = (float*)wsb;                 wsb += (size_t)ndst * 128 * 4;
    unsigned short* wkT = (unsigned short*)wsb; wsb += 32768 * 2;
    unsigned short* wvT = (unsigned short*)wsb; wsb += 32768 * 2;
    int* cnt    = (int*)wsb;                    wsb += (size_t)ndst * 4;
    int* rs     = (int*)wsb;                    wsb += (size_t)ndst * 4;
    int* fill   = (int*)wsb;                    wsb += (size_t)ndst * 4;
    int* bsum   = (int*)wsb;                    wsb += 1024;
    int* epos   = (int*)wsb;                    wsb += (size_t)E * 4;
    float2* att2 = (float2*)wsb;                wsb += (size_t)E * 8;
    unsigned short* Vbuf = (unsigned short*)wsb; wsb += (size_t)E * 128 * 2;

    k_zero<<<256, 256, 0, stream>>>(cnt, fill, ndst);
    k_prep<<<1, 128, 0, stream>>>(qbias, wq_w, wq_b, time_b);
    k_pack<<<128, 256, 0, stream>>>(wkT, wvT, wk_w, wv_w);
    k_count<<<(E + 255) / 256, 256, 0, stream>>>(edst, cnt, E);
    k_scan1<<<nblk, 256, 0, stream>>>(cnt, rs, bsum, ndst);
    k_scan2<<<1, 256, 0, stream>>>(bsum, nblk);
    k_scan3<<<nblk, 256, 0, stream>>>(rs, bsum, ndst);
    k_scatter<<<(E + 255) / 256, 256, 0, stream>>>(edst, rs, fill, epos, E);
    k_q<<<(ndst + 63) / 64, 256, 0, stream>>>(Q, h, wq_w, qbias, ndst);
    k_kvA<<<(E + 63) / 64, 256, 0, stream>>>(h, nbr, edst, dt, ef, time_w, time_b,
                                             wkT, wvT, wk_b, Q, epos, Vbuf, att2, ndst, E);
    k_agg<<<(ndst + 3) / 4, 256, 0, stream>>>(Vbuf, att2, rs, cnt, wv_b, agg, ndst);
    k_out<<<(ndst + 63) / 64, 256, 0, stream>>>(agg, h, wo_w, wo_b, ln_g, ln_b,
                                                (float*)d_out, ndst);
}

// Round 9
// 342.899 us; speedup vs baseline: 3.5222x; 1.4852x over previous
//
#include <hip/hip_runtime.h>
#include <hip/hip_bf16.h>
#include <math.h>

// TemporalTransformerConv (TGAT-like) for MI355X — round 9.
// k_kvA: B-operand tables (wkT/wvT, 128 KB) staged through a 32 KB LDS
// half-table (4 phases), XOR-swizzled for conflict-free ds_read_b128.
// Cuts per-CU L2 re-fetch of B 4x (was ~512 KB per 4-wave block, now 128 KB).
// Rest of the pipeline identical to round 8.

using bf16 = __hip_bfloat16;
typedef __attribute__((ext_vector_type(8))) short short8;
typedef __attribute__((ext_vector_type(4))) float f32x4;

static __device__ __forceinline__ unsigned short bf16_bits(float x) {
    bf16 h = __float2bfloat16(x);
    unsigned short b;
    __builtin_memcpy(&b, &h, 2);
    return b;
}
static __device__ __forceinline__ unsigned pk2(float x, float y) {
    return (unsigned)bf16_bits(x) | ((unsigned)bf16_bits(y) << 16);
}
static __device__ __forceinline__ float bflo(unsigned u) {
    return __uint_as_float(u << 16);
}
static __device__ __forceinline__ float bfhi(unsigned u) {
    return __uint_as_float(u & 0xffff0000u);
}
union frag_u { short8 s; unsigned u[4]; };

// ------------------------- prep -------------------------
__global__ void k_prep(float* qbias, const float* __restrict__ wq_w,
                       const float* __restrict__ wq_b, const float* __restrict__ time_b) {
    int c = threadIdx.x;
    if (c < 128) {
        float s = wq_b[c];
        for (int j = 0; j < 64; ++j)
            s += cosf(time_b[j]) * wq_w[(128 + j) * 128 + c];
        qbias[c] = s;
    }
}

__global__ void k_pack(unsigned short* wkT, unsigned short* wvT,
                       const float* __restrict__ wk_w, const float* __restrict__ wv_w) {
    int idx = blockIdx.x * blockDim.x + threadIdx.x;  // 32768
    if (idx < 32768) {
        int n = idx >> 8, k = idx & 255;
        wkT[idx] = bf16_bits(wk_w[(size_t)k * 128 + n]);
        wvT[idx] = bf16_bits(wv_w[(size_t)k * 128 + n]);
    }
}

// ------------------------- CSR slot assignment -------------------------
__global__ void k_zero(int* cnt, int* fill, int n) {
    int i = blockIdx.x * blockDim.x + threadIdx.x;
    int stride = gridDim.x * blockDim.x;
    for (; i < n; i += stride) { cnt[i] = 0; fill[i] = 0; }
}

__global__ void k_count(const int* __restrict__ edst, int* cnt, int E) {
    int e = blockIdx.x * 256 + threadIdx.x;
    if (e < E) atomicAdd(&cnt[edst[e]], 1);
}

__global__ void k_scan1(const int* __restrict__ cnt, int* rs, int* bsum, int n) {
    __shared__ int s[256];
    int t = threadIdx.x;
    int i = blockIdx.x * 256 + t;
    int v = (i < n) ? cnt[i] : 0;
    s[t] = v;
    __syncthreads();
    for (int off = 1; off < 256; off <<= 1) {
        int x = (t >= off) ? s[t - off] : 0;
        __syncthreads();
        s[t] += x;
        __syncthreads();
    }
    if (i < n) rs[i] = s[t] - v;
    if (t == 255) bsum[blockIdx.x] = s[255];
}

__global__ void k_scan2(int* bsum, int nblk) {
    __shared__ int s[256];
    int t = threadIdx.x;
    int v = (t < nblk) ? bsum[t] : 0;
    s[t] = v;
    __syncthreads();
    for (int off = 1; off < 256; off <<= 1) {
        int x = (t >= off) ? s[t - off] : 0;
        __syncthreads();
        s[t] += x;
        __syncthreads();
    }
    if (t < nblk) bsum[t] = s[t] - v;
}

__global__ void k_scan3(int* rs, const int* __restrict__ bsum, int n) {
    int i = blockIdx.x * 256 + threadIdx.x;
    if (i < n) rs[i] += bsum[blockIdx.x];
}

__global__ void k_scatter(const int* __restrict__ edst, const int* __restrict__ rs,
                          int* fill, int* epos, int E) {
    int e = blockIdx.x * 256 + threadIdx.x;
    if (e < E) {
        int d = edst[e];
        epos[e] = rs[d] + atomicAdd(&fill[d], 1);
    }
}

// ------------------------- Q projection -------------------------
__global__ __launch_bounds__(256) void k_q(
    float* __restrict__ Q, const float* __restrict__ h,
    const float* __restrict__ wq_w, const float* __restrict__ qbias, int ndst)
{
    __shared__ float As[64 * 128];
    int row0 = blockIdx.x * 64;
    int tid = threadIdx.x;
    for (int idx = tid; idx < 64 * 128; idx += 256) {
        int r = idx >> 7, c = idx & 127;
        int gr = row0 + r;
        As[idx] = (gr < ndst) ? h[(size_t)gr * 128 + c] : 0.f;
    }
    __syncthreads();
    int cg = tid & 31, rg = tid >> 5;
    int c0 = cg * 4;
    float acc[8][4];
    #pragma unroll
    for (int i = 0; i < 8; ++i) { acc[i][0]=0.f; acc[i][1]=0.f; acc[i][2]=0.f; acc[i][3]=0.f; }
    for (int k = 0; k < 128; k += 4) {
        float4 w0 = *reinterpret_cast<const float4*>(wq_w + (size_t)(k+0)*128 + c0);
        float4 w1 = *reinterpret_cast<const float4*>(wq_w + (size_t)(k+1)*128 + c0);
        float4 w2 = *reinterpret_cast<const float4*>(wq_w + (size_t)(k+2)*128 + c0);
        float4 w3 = *reinterpret_cast<const float4*>(wq_w + (size_t)(k+3)*128 + c0);
        #pragma unroll
        for (int i = 0; i < 8; ++i) {
            float4 a = *reinterpret_cast<const float4*>(&As[(rg*8+i)*128 + k]);
            acc[i][0] = fmaf(a.x,w0.x,fmaf(a.y,w1.x,fmaf(a.z,w2.x,fmaf(a.w,w3.x,acc[i][0]))));
            acc[i][1] = fmaf(a.x,w0.y,fmaf(a.y,w1.y,fmaf(a.z,w2.y,fmaf(a.w,w3.y,acc[i][1]))));
            acc[i][2] = fmaf(a.x,w0.z,fmaf(a.y,w1.z,fmaf(a.z,w2.z,fmaf(a.w,w3.z,acc[i][2]))));
            acc[i][3] = fmaf(a.x,w0.w,fmaf(a.y,w1.w,fmaf(a.z,w2.w,fmaf(a.w,w3.w,acc[i][3]))));
        }
    }
    float q0 = qbias[c0], q1 = qbias[c0+1], q2 = qbias[c0+2], q3 = qbias[c0+3];
    #pragma unroll
    for (int i = 0; i < 8; ++i) {
        int r = row0 + rg*8 + i;
        if (r < ndst) {
            float4 o = make_float4(acc[i][0]+q0, acc[i][1]+q1, acc[i][2]+q2, acc[i][3]+q3);
            *reinterpret_cast<float4*>(Q + (size_t)r*128 + c0) = o;
        }
    }
}

// ------------------------- edge pass (LDS-staged B) -------------------------
// LDS half-table: 128 rows (n) x 128 elems (k-half), 256 B/row, XOR-swizzled:
// elem_off = row*128 + ((chunk16 ^ (row&15)) << 3), chunk16 = 16B unit index.
__global__ __launch_bounds__(256) void k_kvA(
    const float* __restrict__ h, const int* __restrict__ nbr, const int* __restrict__ edst,
    const float* __restrict__ dt, const float* __restrict__ ef,
    const float* __restrict__ time_w, const float* __restrict__ time_b,
    const unsigned short* __restrict__ wkT, const unsigned short* __restrict__ wvT,
    const float* __restrict__ wk_b, const float* __restrict__ Q,
    const int* __restrict__ epos,
    unsigned short* __restrict__ Vbuf, float2* __restrict__ att2, int ndst, int E)
{
    __shared__ unsigned short Bs[16384];  // 32 KB
    int tid  = threadIdx.x;
    int lane = tid & 63;
    int l15  = lane & 15;
    int lk   = lane >> 4;
    int e0   = blockIdx.x * 64 + (tid >> 6) * 16;

    // identities
    int  ea = e0 + l15;
    bool va = ea < E;
    int  na = va ? nbr[ea] : 0;
    float da = va ? dt[ea] : 0.f;
    const float* hrow = h + (size_t)(ndst + na) * 128;
    const float* erow = ef + (size_t)ea * 64;

    int dstr[4], pe[4];
    bool evv[4];
    #pragma unroll
    for (int j = 0; j < 4; ++j) {
        int ed = e0 + lk * 4 + j;
        evv[j]  = ed < E;
        dstr[j] = evv[j] ? edst[ed] : 0;
        pe[j]   = evv[j] ? epos[ed] : 0;
    }

    // ---- A-region vector loads (12 independent) ----
    float4 hx[4][2], ex_[2][2];
    const float4 z4 = make_float4(0.f, 0.f, 0.f, 0.f);
    #pragma unroll
    for (int kk = 0; kk < 4; ++kk) {
        int c0 = kk * 32 + lk * 8;
        hx[kk][0] = va ? *reinterpret_cast<const float4*>(hrow + c0)     : z4;
        hx[kk][1] = va ? *reinterpret_cast<const float4*>(hrow + c0 + 4) : z4;
    }
    #pragma unroll
    for (int t = 0; t < 2; ++t) {
        int c = (4 + t) * 32 + lk * 8 - 128;
        ex_[t][0] = va ? *reinterpret_cast<const float4*>(erow + c)     : z4;
        ex_[t][1] = va ? *reinterpret_cast<const float4*>(erow + c + 4) : z4;
    }

    // ---- Q gather (32 independent scalar loads) ----
    float qg[8][4];
    #pragma unroll
    for (int nt = 0; nt < 8; ++nt) {
        int gc = nt * 16 + l15;
        #pragma unroll
        for (int j = 0; j < 4; ++j)
            qg[nt][j] = Q[(size_t)dstr[j] * 128 + gc];
    }

    // ---- stage K half 0 while A/Q loads fly ----
    #pragma unroll
    for (int it = 0; it < 8; ++it) {
        int i = it * 256 + tid;            // 16B-chunk id 0..2047
        int row = i >> 4, c = i & 15;
        uint4 v = *reinterpret_cast<const uint4*>(wkT + (size_t)row * 256 + c * 8);
        *reinterpret_cast<uint4*>(Bs + row * 128 + ((c ^ (row & 15)) << 3)) = v;
    }

    // ---- VALU: time-feature cos ----
    float tf[16];
    {
        int j0 = lk * 8;
        #pragma unroll
        for (int t = 0; t < 8; ++t) tf[t]     = __cosf(fmaf(da, time_w[j0 + t],      time_b[j0 + t]));
        #pragma unroll
        for (int t = 0; t < 8; ++t) tf[8 + t] = __cosf(fmaf(da, time_w[j0 + 32 + t], time_b[j0 + 32 + t]));
    }

    // ---- pack A fragments ----
    frag_u a[8];
    #pragma unroll
    for (int kk = 0; kk < 4; ++kk) {
        a[kk].u[0] = pk2(hx[kk][0].x, hx[kk][0].y); a[kk].u[1] = pk2(hx[kk][0].z, hx[kk][0].w);
        a[kk].u[2] = pk2(hx[kk][1].x, hx[kk][1].y); a[kk].u[3] = pk2(hx[kk][1].z, hx[kk][1].w);
    }
    #pragma unroll
    for (int t = 0; t < 2; ++t) {
        a[4+t].u[0] = pk2(ex_[t][0].x, ex_[t][0].y); a[4+t].u[1] = pk2(ex_[t][0].z, ex_[t][0].w);
        a[4+t].u[2] = pk2(ex_[t][1].x, ex_[t][1].y); a[4+t].u[3] = pk2(ex_[t][1].z, ex_[t][1].w);
    }
    a[6].u[0] = pk2(tf[0], tf[1]);  a[6].u[1] = pk2(tf[2], tf[3]);
    a[6].u[2] = pk2(tf[4], tf[5]);  a[6].u[3] = pk2(tf[6], tf[7]);
    a[7].u[0] = pk2(tf[8], tf[9]);  a[7].u[1] = pk2(tf[10], tf[11]);
    a[7].u[2] = pk2(tf[12], tf[13]); a[7].u[3] = pk2(tf[14], tf[15]);

    f32x4 ck[8];
    #pragma unroll
    for (int nt = 0; nt < 8; ++nt) ck[nt] = (f32x4){0.f, 0.f, 0.f, 0.f};

    // ---- K GEMM phase 0 (kk 0..3 from LDS) ----
    __syncthreads();
    #pragma unroll
    for (int kk2 = 0; kk2 < 4; ++kk2) {
        int co = ((kk2 * 4 + lk) ^ l15) << 3;
        #pragma unroll
        for (int nt = 0; nt < 8; ++nt) {
            short8 b = *reinterpret_cast<const short8*>(Bs + (nt * 16 + l15) * 128 + co);
            ck[nt] = __builtin_amdgcn_mfma_f32_16x16x32_bf16(a[kk2].s, b, ck[nt], 0, 0, 0);
        }
    }
    __syncthreads();
    // ---- stage K half 1, GEMM phase 1 ----
    #pragma unroll
    for (int it = 0; it < 8; ++it) {
        int i = it * 256 + tid;
        int row = i >> 4, c = i & 15;
        uint4 v = *reinterpret_cast<const uint4*>(wkT + (size_t)row * 256 + 128 + c * 8);
        *reinterpret_cast<uint4*>(Bs + row * 128 + ((c ^ (row & 15)) << 3)) = v;
    }
    __syncthreads();
    #pragma unroll
    for (int kk2 = 0; kk2 < 4; ++kk2) {
        int co = ((kk2 * 4 + lk) ^ l15) << 3;
        #pragma unroll
        for (int nt = 0; nt < 8; ++nt) {
            short8 b = *reinterpret_cast<const short8*>(Bs + (nt * 16 + l15) * 128 + co);
            ck[nt] = __builtin_amdgcn_mfma_f32_16x16x32_bf16(a[4 + kk2].s, b, ck[nt], 0, 0, 0);
        }
    }
    __syncthreads();
    // ---- stage V half 0 (att section overlaps these loads) ----
    #pragma unroll
    for (int it = 0; it < 8; ++it) {
        int i = it * 256 + tid;
        int row = i >> 4, c = i & 15;
        uint4 v = *reinterpret_cast<const uint4*>(wvT + (size_t)row * 256 + c * 8);
        *reinterpret_cast<uint4*>(Bs + row * 128 + ((c ^ (row & 15)) << 3)) = v;
    }

    // ---- att dot per head + 16-lane reduce, leaky, store ----
    float p0[4], p1[4];
    #pragma unroll
    for (int j = 0; j < 4; ++j) { p0[j] = 0.f; p1[j] = 0.f; }
    #pragma unroll
    for (int nt = 0; nt < 8; ++nt) {
        float kb = wk_b[nt * 16 + l15];
        #pragma unroll
        for (int j = 0; j < 4; ++j) {
            float t = (ck[nt][j] + kb) * qg[nt][j];
            if (nt < 4) p0[j] += t; else p1[j] += t;
        }
    }
    #pragma unroll
    for (int m = 1; m <= 8; m <<= 1)
        #pragma unroll
        for (int j = 0; j < 4; ++j) {
            p0[j] += __shfl_xor(p0[j], m, 64);
            p1[j] += __shfl_xor(p1[j], m, 64);
        }
    if (l15 == 0) {
        #pragma unroll
        for (int j = 0; j < 4; ++j)
            if (evv[j]) {
                float r0 = p0[j]; r0 = (r0 >= 0.f) ? r0 : 0.2f * r0;
                float r1 = p1[j]; r1 = (r1 >= 0.f) ? r1 : 0.2f * r1;
                att2[pe[j]] = make_float2(r0, r1);
            }
    }

    // ---- V GEMM phase 0 ----
    f32x4 cv[8];
    #pragma unroll
    for (int nt = 0; nt < 8; ++nt) cv[nt] = (f32x4){0.f, 0.f, 0.f, 0.f};
    __syncthreads();
    #pragma unroll
    for (int kk2 = 0; kk2 < 4; ++kk2) {
        int co = ((kk2 * 4 + lk) ^ l15) << 3;
        #pragma unroll
        for (int nt = 0; nt < 8; ++nt) {
            short8 b = *reinterpret_cast<const short8*>(Bs + (nt * 16 + l15) * 128 + co);
            cv[nt] = __builtin_amdgcn_mfma_f32_16x16x32_bf16(a[kk2].s, b, cv[nt], 0, 0, 0);
        }
    }
    __syncthreads();
    // ---- stage V half 1, GEMM phase 1 ----
    #pragma unroll
    for (int it = 0; it < 8; ++it) {
        int i = it * 256 + tid;
        int row = i >> 4, c = i & 15;
        uint4 v = *reinterpret_cast<const uint4*>(wvT + (size_t)row * 256 + 128 + c * 8);
        *reinterpret_cast<uint4*>(Bs + row * 128 + ((c ^ (row & 15)) << 3)) = v;
    }
    __syncthreads();
    #pragma unroll
    for (int kk2 = 0; kk2 < 4; ++kk2) {
        int co = ((kk2 * 4 + lk) ^ l15) << 3;
        #pragma unroll
        for (int nt = 0; nt < 8; ++nt) {
            short8 b = *reinterpret_cast<const short8*>(Bs + (nt * 16 + l15) * 128 + co);
            cv[nt] = __builtin_amdgcn_mfma_f32_16x16x32_bf16(a[4 + kk2].s, b, cv[nt], 0, 0, 0);
        }
    }

    // ---- store raw V rows, col-permuted: pos = l15*8 + nt ----
    #pragma unroll
    for (int j = 0; j < 4; ++j)
        if (evv[j]) {
            uint4 val;
            val.x = pk2(cv[0][j], cv[1][j]);
            val.y = pk2(cv[2][j], cv[3][j]);
            val.z = pk2(cv[4][j], cv[5][j]);
            val.w = pk2(cv[6][j], cv[7][j]);
            *reinterpret_cast<uint4*>(Vbuf + (size_t)pe[j] * 128 + l15 * 8) = val;
        }
}

// ------------------------- streaming segment reduction -------------------------
__global__ __launch_bounds__(256) void k_agg(
    const unsigned short* __restrict__ Vbuf, const float2* __restrict__ att2,
    const int* __restrict__ rs, const int* __restrict__ cnt,
    const float* __restrict__ wv_b, float* __restrict__ agg, int ndst)
{
    int w = threadIdx.x >> 6, lane = threadIdx.x & 63;
    int d = blockIdx.x * 4 + w;
    if (d >= ndst) return;
    int p0 = lane * 2, p1 = p0 + 1;
    int c0 = ((p0 & 7) << 4) + (p0 >> 3);
    int c1 = ((p1 & 7) << 4) + (p1 >> 3);
    bool h0 = (p0 & 4) != 0, h1 = (p1 & 4) != 0;
    int base = rs[d], n = cnt[d];
    const unsigned* V32 = reinterpret_cast<const unsigned*>(Vbuf);
    float den0 = 0.f, den1 = 0.f, acc0 = 0.f, acc1 = 0.f;
    for (int i = 0; i < n; ++i) {
        size_t row = (size_t)(base + i);
        float2 at = att2[row];
        float ex0 = __expf(at.x), ex1 = __expf(at.y);
        den0 += ex0; den1 += ex1;
        unsigned vv = V32[row * 64 + lane];
        acc0 = fmaf(h0 ? ex1 : ex0, bflo(vv), acc0);
        acc1 = fmaf(h1 ? ex1 : ex0, bfhi(vv), acc1);
    }
    float o0 = 0.f, o1 = 0.f;
    if (n > 0) {
        o0 = acc0 / (h0 ? den1 : den0) + wv_b[c0];
        o1 = acc1 / (h1 ? den1 : den0) + wv_b[c1];
    }
    agg[(size_t)d * 128 + c0] = o0;
    agg[(size_t)d * 128 + c1] = o1;
}

// ------------------------- output: GEMM + ReLU + LayerNorm -------------------------
__global__ __launch_bounds__(256) void k_out(
    const float* __restrict__ agg,
    const float* __restrict__ h, const float* __restrict__ wo_w, const float* __restrict__ wo_b,
    const float* __restrict__ ln_g, const float* __restrict__ ln_b,
    float* __restrict__ out, int ndst)
{
    __shared__ float As[64 * 256];
    int row0 = blockIdx.x * 64;
    int tid = threadIdx.x;
    for (int idx = tid; idx < 64 * 256; idx += 256) {
        int r = idx >> 8, c = idx & 255;
        int gr = row0 + r;
        float v = 0.f;
        if (gr < ndst)
            v = (c < 128) ? agg[(size_t)gr * 128 + c] : h[(size_t)gr * 128 + (c - 128)];
        As[idx] = v;
    }
    __syncthreads();
    int cg = tid & 31, rg = tid >> 5;
    int c0 = cg * 4;
    float acc[8][4];
    #pragma unroll
    for (int i = 0; i < 8; ++i) { acc[i][0]=0.f; acc[i][1]=0.f; acc[i][2]=0.f; acc[i][3]=0.f; }
    for (int k = 0; k < 256; k += 4) {
        float4 w0 = *reinterpret_cast<const float4*>(wo_w + (size_t)(k+0)*128 + c0);
        float4 w1 = *reinterpret_cast<const float4*>(wo_w + (size_t)(k+1)*128 + c0);
        float4 w2 = *reinterpret_cast<const float4*>(wo_w + (size_t)(k+2)*128 + c0);
        float4 w3 = *reinterpret_cast<const float4*>(wo_w + (size_t)(k+3)*128 + c0);
        #pragma unroll
        for (int i = 0; i < 8; ++i) {
            float4 a = *reinterpret_cast<const float4*>(&As[(rg*8+i)*256 + k]);
            acc[i][0] = fmaf(a.x,w0.x,fmaf(a.y,w1.x,fmaf(a.z,w2.x,fmaf(a.w,w3.x,acc[i][0]))));
            acc[i][1] = fmaf(a.x,w0.y,fmaf(a.y,w1.y,fmaf(a.z,w2.y,fmaf(a.w,w3.y,acc[i][1]))));
            acc[i][2] = fmaf(a.x,w0.z,fmaf(a.y,w1.z,fmaf(a.z,w2.z,fmaf(a.w,w3.z,acc[i][2]))));
            acc[i][3] = fmaf(a.x,w0.w,fmaf(a.y,w1.w,fmaf(a.z,w2.w,fmaf(a.w,w3.w,acc[i][3]))));
        }
    }
    float b0 = wo_b[c0], b1 = wo_b[c0+1], b2 = wo_b[c0+2], b3 = wo_b[c0+3];
    float g0 = ln_g[c0], g1 = ln_g[c0+1], g2 = ln_g[c0+2], g3 = ln_g[c0+3];
    float l0 = ln_b[c0], l1 = ln_b[c0+1], l2 = ln_b[c0+2], l3 = ln_b[c0+3];
    #pragma unroll
    for (int i = 0; i < 8; ++i) {
        float x0 = fmaxf(acc[i][0] + b0, 0.f);
        float x1 = fmaxf(acc[i][1] + b1, 0.f);
        float x2 = fmaxf(acc[i][2] + b2, 0.f);
        float x3 = fmaxf(acc[i][3] + b3, 0.f);
        float s1 = x0 + x1 + x2 + x3;
        float s2 = x0*x0 + x1*x1 + x2*x2 + x3*x3;
        #pragma unroll
        for (int mm = 1; mm <= 16; mm <<= 1) {
            s1 += __shfl_xor(s1, mm, 64);
            s2 += __shfl_xor(s2, mm, 64);
        }
        float mean = s1 * (1.f / 128.f);
        float var  = s2 * (1.f / 128.f) - mean * mean;
        float rstd = rsqrtf(var + 1e-5f);
        int r = row0 + rg * 8 + i;
        if (r < ndst) {
            float4 o = make_float4((x0 - mean) * rstd * g0 + l0,
                                   (x1 - mean) * rstd * g1 + l1,
                                   (x2 - mean) * rstd * g2 + l2,
                                   (x3 - mean) * rstd * g3 + l3);
            *reinterpret_cast<float4*>(out + (size_t)r * 128 + c0) = o;
        }
    }
}

extern "C" void kernel_launch(void* const* d_in, const int* in_sizes, int n_in,
                              void* d_out, int out_size, void* d_ws, size_t ws_size,
                              hipStream_t stream) {
    const float* h      = (const float*)d_in[0];
    const float* dt     = (const float*)d_in[1];
    const float* ef     = (const float*)d_in[2];
    const float* time_w = (const float*)d_in[3];
    const float* time_b = (const float*)d_in[4];
    const float* wq_w   = (const float*)d_in[5];
    const float* wq_b   = (const float*)d_in[6];
    const float* wk_w   = (const float*)d_in[7];
    const float* wk_b   = (const float*)d_in[8];
    const float* wv_w   = (const float*)d_in[9];
    const float* wv_b   = (const float*)d_in[10];
    const float* wo_w   = (const float*)d_in[11];
    const float* wo_b   = (const float*)d_in[12];
    const float* ln_g   = (const float*)d_in[13];
    const float* ln_b   = (const float*)d_in[14];
    const int* nbr      = (const int*)d_in[15];
    const int* edst     = (const int*)d_in[16];

    int E    = in_sizes[1];
    int ndst = out_size / 128;
    int nblk = (ndst + 255) / 256;

    char* wsb = (char*)d_ws;
    float* qbias = (float*)wsb;                 wsb += 512;
    float* Q     = (float*)wsb;                 wsb += (size_t)ndst * 128 * 4;
    float* agg   = (float*)wsb;                 wsb += (size_t)ndst * 128 * 4;
    unsigned short* wkT = (unsigned short*)wsb; wsb += 32768 * 2;
    unsigned short* wvT = (unsigned short*)wsb; wsb += 32768 * 2;
    int* cnt    = (int*)wsb;                    wsb += (size_t)ndst * 4;
    int* rs     = (int*)wsb;                    wsb += (size_t)ndst * 4;
    int* fill   = (int*)wsb;                    wsb += (size_t)ndst * 4;
    int* bsum   = (int*)wsb;                    wsb += 1024;
    int* epos   = (int*)wsb;                    wsb += (size_t)E * 4;
    float2* att2 = (float2*)wsb;                wsb += (size_t)E * 8;
    unsigned short* Vbuf = (unsigned short*)wsb; wsb += (size_t)E * 128 * 2;

    k_zero<<<256, 256, 0, stream>>>(cnt, fill, ndst);
    k_prep<<<1, 128, 0, stream>>>(qbias, wq_w, wq_b, time_b);
    k_pack<<<128, 256, 0, stream>>>(wkT, wvT, wk_w, wv_w);
    k_count<<<(E + 255) / 256, 256, 0, stream>>>(edst, cnt, E);
    k_scan1<<<nblk, 256, 0, stream>>>(cnt, rs, bsum, ndst);
    k_scan2<<<1, 256, 0, stream>>>(bsum, nblk);
    k_scan3<<<nblk, 256, 0, stream>>>(rs, bsum, ndst);
    k_scatter<<<(E + 255) / 256, 256, 0, stream>>>(edst, rs, fill, epos, E);
    k_q<<<(ndst + 63) / 64, 256, 0, stream>>>(Q, h, wq_w, qbias, ndst);
    k_kvA<<<(E + 63) / 64, 256, 0, stream>>>(h, nbr, edst, dt, ef, time_w, time_b,
                                             wkT, wvT, wk_b, Q, epos, Vbuf, att2, ndst, E);
    k_agg<<<(ndst + 3) / 4, 256, 0, stream>>>(Vbuf, att2, rs, cnt, wv_b, agg, ndst);
    k_out<<<(ndst + 63) / 64, 256, 0, stream>>>(agg, h, wo_w, wo_b, ln_g, ln_b,
                                                (float*)d_out, ndst);
}

// Round 10
// 248.879 us; speedup vs baseline: 4.8528x; 1.3778x over previous
//
#include <hip/hip_runtime.h>
#include <hip/hip_bf16.h>
#include <math.h>

// TemporalTransformerConv (TGAT-like) for MI355X — round 10.
// k_q and k_out converted to MFMA with 32 KB LDS-staged swizzled B tables
// (same structure as k_kvA). k_q uses split-bf16 (hi+lo) for f32-level
// accuracy since Q feeds exp(); k_out uses plain bf16 (feeds LN, safe).
// k_zero replaced by hipMemsetAsync.

using bf16 = __hip_bfloat16;
typedef __attribute__((ext_vector_type(8))) short short8;
typedef __attribute__((ext_vector_type(4))) float f32x4;

static __device__ __forceinline__ unsigned short bf16_bits(float x) {
    bf16 h = __float2bfloat16(x);
    unsigned short b;
    __builtin_memcpy(&b, &h, 2);
    return b;
}
static __device__ __forceinline__ unsigned pk2(float x, float y) {
    return (unsigned)bf16_bits(x) | ((unsigned)bf16_bits(y) << 16);
}
static __device__ __forceinline__ float bflo(unsigned u) {
    return __uint_as_float(u << 16);
}
static __device__ __forceinline__ float bfhi(unsigned u) {
    return __uint_as_float(u & 0xffff0000u);
}
union frag_u { short8 s; unsigned u[4]; };

// ------------------------- prep -------------------------
__global__ void k_prep(float* qbias, const float* __restrict__ wq_w,
                       const float* __restrict__ wq_b, const float* __restrict__ time_b) {
    int c = threadIdx.x;
    if (c < 128) {
        float s = wq_b[c];
        for (int j = 0; j < 64; ++j)
            s += cosf(time_b[j]) * wq_w[(128 + j) * 128 + c];
        qbias[c] = s;
    }
}

// pack: wk/wv/wo -> bf16 [n][k] transposed; wq -> split hi/lo bf16 [n=128][k=128]
__global__ void k_pack(unsigned short* wkT, unsigned short* wvT, unsigned short* woT,
                       unsigned short* wqhT, unsigned short* wqlT,
                       const float* __restrict__ wk_w, const float* __restrict__ wv_w,
                       const float* __restrict__ wo_w, const float* __restrict__ wq_w) {
    int idx = blockIdx.x * blockDim.x + threadIdx.x;  // 32768
    if (idx < 32768) {
        int n = idx >> 8, k = idx & 255;
        wkT[idx] = bf16_bits(wk_w[(size_t)k * 128 + n]);
        wvT[idx] = bf16_bits(wv_w[(size_t)k * 128 + n]);
        woT[idx] = bf16_bits(wo_w[(size_t)k * 128 + n]);
        if (idx < 16384) {
            int n2 = idx >> 7, k2 = idx & 127;
            float v = wq_w[(size_t)k2 * 128 + n2];
            unsigned short hb = bf16_bits(v);
            wqhT[idx] = hb;
            wqlT[idx] = bf16_bits(v - __uint_as_float((unsigned)hb << 16));
        }
    }
}

// ------------------------- CSR slot assignment -------------------------
__global__ void k_count(const int* __restrict__ edst, int* cnt, int E) {
    int e = blockIdx.x * 256 + threadIdx.x;
    if (e < E) atomicAdd(&cnt[edst[e]], 1);
}

__global__ void k_scan1(const int* __restrict__ cnt, int* rs, int* bsum, int n) {
    __shared__ int s[256];
    int t = threadIdx.x;
    int i = blockIdx.x * 256 + t;
    int v = (i < n) ? cnt[i] : 0;
    s[t] = v;
    __syncthreads();
    for (int off = 1; off < 256; off <<= 1) {
        int x = (t >= off) ? s[t - off] : 0;
        __syncthreads();
        s[t] += x;
        __syncthreads();
    }
    if (i < n) rs[i] = s[t] - v;
    if (t == 255) bsum[blockIdx.x] = s[255];
}

__global__ void k_scan2(int* bsum, int nblk) {
    __shared__ int s[256];
    int t = threadIdx.x;
    int v = (t < nblk) ? bsum[t] : 0;
    s[t] = v;
    __syncthreads();
    for (int off = 1; off < 256; off <<= 1) {
        int x = (t >= off) ? s[t - off] : 0;
        __syncthreads();
        s[t] += x;
        __syncthreads();
    }
    if (t < nblk) bsum[t] = s[t] - v;
}

__global__ void k_scan3(int* rs, const int* __restrict__ bsum, int n) {
    int i = blockIdx.x * 256 + threadIdx.x;
    if (i < n) rs[i] += bsum[blockIdx.x];
}

__global__ void k_scatter(const int* __restrict__ edst, const int* __restrict__ rs,
                          int* fill, int* epos, int E) {
    int e = blockIdx.x * 256 + threadIdx.x;
    if (e < E) {
        int d = edst[e];
        epos[e] = rs[d] + atomicAdd(&fill[d], 1);
    }
}

// ------------------------- Q projection (split-bf16 MFMA) -------------------------
// Q = h_dst @ wq[0:128] + qbias ;  h = hi+lo, W = Whi+Wlo ;
// Q ~= hi*Whi + hi*Wlo + lo*Whi  (error ~2^-16 relative)
__global__ __launch_bounds__(256) void k_q(
    float* __restrict__ Q, const float* __restrict__ h,
    const unsigned short* __restrict__ wqhT, const unsigned short* __restrict__ wqlT,
    const float* __restrict__ qbias, int ndst)
{
    __shared__ unsigned short Bs[16384];  // 32 KB: [n=128][k=128] swizzled
    int tid = threadIdx.x;
    int lane = tid & 63, l15 = lane & 15, lk = lane >> 4;
    int r0 = blockIdx.x * 64 + (tid >> 6) * 16;
    int ra = r0 + l15;
    int rc = (ra < ndst) ? ra : (ndst - 1);
    const float* hrow = h + (size_t)rc * 128;

    // A loads (8 independent float4)
    float4 hx[4][2];
    #pragma unroll
    for (int kk = 0; kk < 4; ++kk) {
        int c0 = kk * 32 + lk * 8;
        hx[kk][0] = *reinterpret_cast<const float4*>(hrow + c0);
        hx[kk][1] = *reinterpret_cast<const float4*>(hrow + c0 + 4);
    }

    // stage Whi (2048 16B-chunks; row=128 elems=16 chunks)
    #pragma unroll
    for (int it = 0; it < 8; ++it) {
        int i = it * 256 + tid;
        int row = i >> 4, c = i & 15;
        uint4 v = *reinterpret_cast<const uint4*>(wqhT + (size_t)row * 128 + c * 8);
        *reinterpret_cast<uint4*>(Bs + row * 128 + ((c ^ (row & 15)) << 3)) = v;
    }

    // split-pack A frags
    frag_u ah[4], al[4];
    #pragma unroll
    for (int kk = 0; kk < 4; ++kk) {
        float xs[8] = {hx[kk][0].x, hx[kk][0].y, hx[kk][0].z, hx[kk][0].w,
                       hx[kk][1].x, hx[kk][1].y, hx[kk][1].z, hx[kk][1].w};
        unsigned short hb[8];
        float lo[8];
        #pragma unroll
        for (int t = 0; t < 8; ++t) {
            hb[t] = bf16_bits(xs[t]);
            lo[t] = xs[t] - __uint_as_float((unsigned)hb[t] << 16);
        }
        #pragma unroll
        for (int t = 0; t < 4; ++t)
            ah[kk].u[t] = (unsigned)hb[2*t] | ((unsigned)hb[2*t+1] << 16);
        al[kk].u[0] = pk2(lo[0], lo[1]); al[kk].u[1] = pk2(lo[2], lo[3]);
        al[kk].u[2] = pk2(lo[4], lo[5]); al[kk].u[3] = pk2(lo[6], lo[7]);
    }

    f32x4 ck[8];
    #pragma unroll
    for (int nt = 0; nt < 8; ++nt) ck[nt] = (f32x4){0.f, 0.f, 0.f, 0.f};

    __syncthreads();
    // hi*Whi + lo*Whi
    #pragma unroll
    for (int kk2 = 0; kk2 < 4; ++kk2) {
        int co = ((kk2 * 4 + lk) ^ l15) << 3;
        #pragma unroll
        for (int nt = 0; nt < 8; ++nt) {
            short8 b = *reinterpret_cast<const short8*>(Bs + (nt * 16 + l15) * 128 + co);
            ck[nt] = __builtin_amdgcn_mfma_f32_16x16x32_bf16(ah[kk2].s, b, ck[nt], 0, 0, 0);
            ck[nt] = __builtin_amdgcn_mfma_f32_16x16x32_bf16(al[kk2].s, b, ck[nt], 0, 0, 0);
        }
    }
    __syncthreads();
    // stage Wlo
    #pragma unroll
    for (int it = 0; it < 8; ++it) {
        int i = it * 256 + tid;
        int row = i >> 4, c = i & 15;
        uint4 v = *reinterpret_cast<const uint4*>(wqlT + (size_t)row * 128 + c * 8);
        *reinterpret_cast<uint4*>(Bs + row * 128 + ((c ^ (row & 15)) << 3)) = v;
    }
    __syncthreads();
    // hi*Wlo
    #pragma unroll
    for (int kk2 = 0; kk2 < 4; ++kk2) {
        int co = ((kk2 * 4 + lk) ^ l15) << 3;
        #pragma unroll
        for (int nt = 0; nt < 8; ++nt) {
            short8 b = *reinterpret_cast<const short8*>(Bs + (nt * 16 + l15) * 128 + co);
            ck[nt] = __builtin_amdgcn_mfma_f32_16x16x32_bf16(ah[kk2].s, b, ck[nt], 0, 0, 0);
        }
    }

    // epilogue: + qbias, store
    #pragma unroll
    for (int nt = 0; nt < 8; ++nt) {
        int col = nt * 16 + l15;
        float qb = qbias[col];
        #pragma unroll
        for (int j = 0; j < 4; ++j) {
            int row = r0 + lk * 4 + j;
            if (row < ndst) Q[(size_t)row * 128 + col] = ck[nt][j] + qb;
        }
    }
}

// ------------------------- edge pass (LDS-staged B) -------------------------
__global__ __launch_bounds__(256) void k_kvA(
    const float* __restrict__ h, const int* __restrict__ nbr, const int* __restrict__ edst,
    const float* __restrict__ dt, const float* __restrict__ ef,
    const float* __restrict__ time_w, const float* __restrict__ time_b,
    const unsigned short* __restrict__ wkT, const unsigned short* __restrict__ wvT,
    const float* __restrict__ wk_b, const float* __restrict__ Q,
    const int* __restrict__ epos,
    unsigned short* __restrict__ Vbuf, float2* __restrict__ att2, int ndst, int E)
{
    __shared__ unsigned short Bs[16384];  // 32 KB
    int tid  = threadIdx.x;
    int lane = tid & 63;
    int l15  = lane & 15;
    int lk   = lane >> 4;
    int e0   = blockIdx.x * 64 + (tid >> 6) * 16;

    int  ea = e0 + l15;
    bool va = ea < E;
    int  na = va ? nbr[ea] : 0;
    float da = va ? dt[ea] : 0.f;
    const float* hrow = h + (size_t)(ndst + na) * 128;
    const float* erow = ef + (size_t)ea * 64;

    int dstr[4], pe[4];
    bool evv[4];
    #pragma unroll
    for (int j = 0; j < 4; ++j) {
        int ed = e0 + lk * 4 + j;
        evv[j]  = ed < E;
        dstr[j] = evv[j] ? edst[ed] : 0;
        pe[j]   = evv[j] ? epos[ed] : 0;
    }

    float4 hx[4][2], ex_[2][2];
    const float4 z4 = make_float4(0.f, 0.f, 0.f, 0.f);
    #pragma unroll
    for (int kk = 0; kk < 4; ++kk) {
        int c0 = kk * 32 + lk * 8;
        hx[kk][0] = va ? *reinterpret_cast<const float4*>(hrow + c0)     : z4;
        hx[kk][1] = va ? *reinterpret_cast<const float4*>(hrow + c0 + 4) : z4;
    }
    #pragma unroll
    for (int t = 0; t < 2; ++t) {
        int c = (4 + t) * 32 + lk * 8 - 128;
        ex_[t][0] = va ? *reinterpret_cast<const float4*>(erow + c)     : z4;
        ex_[t][1] = va ? *reinterpret_cast<const float4*>(erow + c + 4) : z4;
    }

    float qg[8][4];
    #pragma unroll
    for (int nt = 0; nt < 8; ++nt) {
        int gc = nt * 16 + l15;
        #pragma unroll
        for (int j = 0; j < 4; ++j)
            qg[nt][j] = Q[(size_t)dstr[j] * 128 + gc];
    }

    #pragma unroll
    for (int it = 0; it < 8; ++it) {
        int i = it * 256 + tid;
        int row = i >> 4, c = i & 15;
        uint4 v = *reinterpret_cast<const uint4*>(wkT + (size_t)row * 256 + c * 8);
        *reinterpret_cast<uint4*>(Bs + row * 128 + ((c ^ (row & 15)) << 3)) = v;
    }

    float tf[16];
    {
        int j0 = lk * 8;
        #pragma unroll
        for (int t = 0; t < 8; ++t) tf[t]     = __cosf(fmaf(da, time_w[j0 + t],      time_b[j0 + t]));
        #pragma unroll
        for (int t = 0; t < 8; ++t) tf[8 + t] = __cosf(fmaf(da, time_w[j0 + 32 + t], time_b[j0 + 32 + t]));
    }

    frag_u a[8];
    #pragma unroll
    for (int kk = 0; kk < 4; ++kk) {
        a[kk].u[0] = pk2(hx[kk][0].x, hx[kk][0].y); a[kk].u[1] = pk2(hx[kk][0].z, hx[kk][0].w);
        a[kk].u[2] = pk2(hx[kk][1].x, hx[kk][1].y); a[kk].u[3] = pk2(hx[kk][1].z, hx[kk][1].w);
    }
    #pragma unroll
    for (int t = 0; t < 2; ++t) {
        a[4+t].u[0] = pk2(ex_[t][0].x, ex_[t][0].y); a[4+t].u[1] = pk2(ex_[t][0].z, ex_[t][0].w);
        a[4+t].u[2] = pk2(ex_[t][1].x, ex_[t][1].y); a[4+t].u[3] = pk2(ex_[t][1].z, ex_[t][1].w);
    }
    a[6].u[0] = pk2(tf[0], tf[1]);  a[6].u[1] = pk2(tf[2], tf[3]);
    a[6].u[2] = pk2(tf[4], tf[5]);  a[6].u[3] = pk2(tf[6], tf[7]);
    a[7].u[0] = pk2(tf[8], tf[9]);  a[7].u[1] = pk2(tf[10], tf[11]);
    a[7].u[2] = pk2(tf[12], tf[13]); a[7].u[3] = pk2(tf[14], tf[15]);

    f32x4 ck[8];
    #pragma unroll
    for (int nt = 0; nt < 8; ++nt) ck[nt] = (f32x4){0.f, 0.f, 0.f, 0.f};

    __syncthreads();
    #pragma unroll
    for (int kk2 = 0; kk2 < 4; ++kk2) {
        int co = ((kk2 * 4 + lk) ^ l15) << 3;
        #pragma unroll
        for (int nt = 0; nt < 8; ++nt) {
            short8 b = *reinterpret_cast<const short8*>(Bs + (nt * 16 + l15) * 128 + co);
            ck[nt] = __builtin_amdgcn_mfma_f32_16x16x32_bf16(a[kk2].s, b, ck[nt], 0, 0, 0);
        }
    }
    __syncthreads();
    #pragma unroll
    for (int it = 0; it < 8; ++it) {
        int i = it * 256 + tid;
        int row = i >> 4, c = i & 15;
        uint4 v = *reinterpret_cast<const uint4*>(wkT + (size_t)row * 256 + 128 + c * 8);
        *reinterpret_cast<uint4*>(Bs + row * 128 + ((c ^ (row & 15)) << 3)) = v;
    }
    __syncthreads();
    #pragma unroll
    for (int kk2 = 0; kk2 < 4; ++kk2) {
        int co = ((kk2 * 4 + lk) ^ l15) << 3;
        #pragma unroll
        for (int nt = 0; nt < 8; ++nt) {
            short8 b = *reinterpret_cast<const short8*>(Bs + (nt * 16 + l15) * 128 + co);
            ck[nt] = __builtin_amdgcn_mfma_f32_16x16x32_bf16(a[4 + kk2].s, b, ck[nt], 0, 0, 0);
        }
    }
    __syncthreads();
    #pragma unroll
    for (int it = 0; it < 8; ++it) {
        int i = it * 256 + tid;
        int row = i >> 4, c = i & 15;
        uint4 v = *reinterpret_cast<const uint4*>(wvT + (size_t)row * 256 + c * 8);
        *reinterpret_cast<uint4*>(Bs + row * 128 + ((c ^ (row & 15)) << 3)) = v;
    }

    float p0[4], p1[4];
    #pragma unroll
    for (int j = 0; j < 4; ++j) { p0[j] = 0.f; p1[j] = 0.f; }
    #pragma unroll
    for (int nt = 0; nt < 8; ++nt) {
        float kb = wk_b[nt * 16 + l15];
        #pragma unroll
        for (int j = 0; j < 4; ++j) {
            float t = (ck[nt][j] + kb) * qg[nt][j];
            if (nt < 4) p0[j] += t; else p1[j] += t;
        }
    }
    #pragma unroll
    for (int m = 1; m <= 8; m <<= 1)
        #pragma unroll
        for (int j = 0; j < 4; ++j) {
            p0[j] += __shfl_xor(p0[j], m, 64);
            p1[j] += __shfl_xor(p1[j], m, 64);
        }
    if (l15 == 0) {
        #pragma unroll
        for (int j = 0; j < 4; ++j)
            if (evv[j]) {
                float r0 = p0[j]; r0 = (r0 >= 0.f) ? r0 : 0.2f * r0;
                float r1 = p1[j]; r1 = (r1 >= 0.f) ? r1 : 0.2f * r1;
                att2[pe[j]] = make_float2(r0, r1);
            }
    }

    f32x4 cv[8];
    #pragma unroll
    for (int nt = 0; nt < 8; ++nt) cv[nt] = (f32x4){0.f, 0.f, 0.f, 0.f};
    __syncthreads();
    #pragma unroll
    for (int kk2 = 0; kk2 < 4; ++kk2) {
        int co = ((kk2 * 4 + lk) ^ l15) << 3;
        #pragma unroll
        for (int nt = 0; nt < 8; ++nt) {
            short8 b = *reinterpret_cast<const short8*>(Bs + (nt * 16 + l15) * 128 + co);
            cv[nt] = __builtin_amdgcn_mfma_f32_16x16x32_bf16(a[kk2].s, b, cv[nt], 0, 0, 0);
        }
    }
    __syncthreads();
    #pragma unroll
    for (int it = 0; it < 8; ++it) {
        int i = it * 256 + tid;
        int row = i >> 4, c = i & 15;
        uint4 v = *reinterpret_cast<const uint4*>(wvT + (size_t)row * 256 + 128 + c * 8);
        *reinterpret_cast<uint4*>(Bs + row * 128 + ((c ^ (row & 15)) << 3)) = v;
    }
    __syncthreads();
    #pragma unroll
    for (int kk2 = 0; kk2 < 4; ++kk2) {
        int co = ((kk2 * 4 + lk) ^ l15) << 3;
        #pragma unroll
        for (int nt = 0; nt < 8; ++nt) {
            short8 b = *reinterpret_cast<const short8*>(Bs + (nt * 16 + l15) * 128 + co);
            cv[nt] = __builtin_amdgcn_mfma_f32_16x16x32_bf16(a[4 + kk2].s, b, cv[nt], 0, 0, 0);
        }
    }

    #pragma unroll
    for (int j = 0; j < 4; ++j)
        if (evv[j]) {
            uint4 val;
            val.x = pk2(cv[0][j], cv[1][j]);
            val.y = pk2(cv[2][j], cv[3][j]);
            val.z = pk2(cv[4][j], cv[5][j]);
            val.w = pk2(cv[6][j], cv[7][j]);
            *reinterpret_cast<uint4*>(Vbuf + (size_t)pe[j] * 128 + l15 * 8) = val;
        }
}

// ------------------------- streaming segment reduction -------------------------
__global__ __launch_bounds__(256) void k_agg(
    const unsigned short* __restrict__ Vbuf, const float2* __restrict__ att2,
    const int* __restrict__ rs, const int* __restrict__ cnt,
    const float* __restrict__ wv_b, float* __restrict__ agg, int ndst)
{
    int w = threadIdx.x >> 6, lane = threadIdx.x & 63;
    int d = blockIdx.x * 4 + w;
    if (d >= ndst) return;
    int p0 = lane * 2, p1 = p0 + 1;
    int c0 = ((p0 & 7) << 4) + (p0 >> 3);
    int c1 = ((p1 & 7) << 4) + (p1 >> 3);
    bool h0 = (p0 & 4) != 0, h1 = (p1 & 4) != 0;
    int base = rs[d], n = cnt[d];
    const unsigned* V32 = reinterpret_cast<const unsigned*>(Vbuf);
    float den0 = 0.f, den1 = 0.f, acc0 = 0.f, acc1 = 0.f;
    for (int i = 0; i < n; ++i) {
        size_t row = (size_t)(base + i);
        float2 at = att2[row];
        float ex0 = __expf(at.x), ex1 = __expf(at.y);
        den0 += ex0; den1 += ex1;
        unsigned vv = V32[row * 64 + lane];
        acc0 = fmaf(h0 ? ex1 : ex0, bflo(vv), acc0);
        acc1 = fmaf(h1 ? ex1 : ex0, bfhi(vv), acc1);
    }
    float o0 = 0.f, o1 = 0.f;
    if (n > 0) {
        o0 = acc0 / (h0 ? den1 : den0) + wv_b[c0];
        o1 = acc1 / (h1 ? den1 : den0) + wv_b[c1];
    }
    agg[(size_t)d * 128 + c0] = o0;
    agg[(size_t)d * 128 + c1] = o1;
}

// ------------------------- output (bf16 MFMA + ReLU + LayerNorm) -------------------------
__global__ __launch_bounds__(256) void k_out(
    const float* __restrict__ agg, const float* __restrict__ h,
    const unsigned short* __restrict__ woT, const float* __restrict__ wo_b,
    const float* __restrict__ ln_g, const float* __restrict__ ln_b,
    float* __restrict__ out, int ndst)
{
    __shared__ unsigned short Bs[16384];  // 32 KB
    int tid = threadIdx.x;
    int lane = tid & 63, l15 = lane & 15, lk = lane >> 4;
    int r0 = blockIdx.x * 64 + (tid >> 6) * 16;
    int ra = r0 + l15;
    int rc = (ra < ndst) ? ra : (ndst - 1);
    const float* arow = agg + (size_t)rc * 128;
    const float* hrow = h + (size_t)rc * 128;

    // A loads: 8 float4 agg + 8 float4 h (16 independent)
    float4 ax[4][2], hx[4][2];
    #pragma unroll
    for (int kk = 0; kk < 4; ++kk) {
        int c0 = kk * 32 + lk * 8;
        ax[kk][0] = *reinterpret_cast<const float4*>(arow + c0);
        ax[kk][1] = *reinterpret_cast<const float4*>(arow + c0 + 4);
        hx[kk][0] = *reinterpret_cast<const float4*>(hrow + c0);
        hx[kk][1] = *reinterpret_cast<const float4*>(hrow + c0 + 4);
    }

    // stage woT half 0 (K 0..127 = agg part)
    #pragma unroll
    for (int it = 0; it < 8; ++it) {
        int i = it * 256 + tid;
        int row = i >> 4, c = i & 15;
        uint4 v = *reinterpret_cast<const uint4*>(woT + (size_t)row * 256 + c * 8);
        *reinterpret_cast<uint4*>(Bs + row * 128 + ((c ^ (row & 15)) << 3)) = v;
    }

    frag_u aa[4], ah[4];
    #pragma unroll
    for (int kk = 0; kk < 4; ++kk) {
        aa[kk].u[0] = pk2(ax[kk][0].x, ax[kk][0].y); aa[kk].u[1] = pk2(ax[kk][0].z, ax[kk][0].w);
        aa[kk].u[2] = pk2(ax[kk][1].x, ax[kk][1].y); aa[kk].u[3] = pk2(ax[kk][1].z, ax[kk][1].w);
        ah[kk].u[0] = pk2(hx[kk][0].x, hx[kk][0].y); ah[kk].u[1] = pk2(hx[kk][0].z, hx[kk][0].w);
        ah[kk].u[2] = pk2(hx[kk][1].x, hx[kk][1].y); ah[kk].u[3] = pk2(hx[kk][1].z, hx[kk][1].w);
    }

    f32x4 ck[8];
    #pragma unroll
    for (int nt = 0; nt < 8; ++nt) ck[nt] = (f32x4){0.f, 0.f, 0.f, 0.f};

    __syncthreads();
    #pragma unroll
    for (int kk2 = 0; kk2 < 4; ++kk2) {
        int co = ((kk2 * 4 + lk) ^ l15) << 3;
        #pragma unroll
        for (int nt = 0; nt < 8; ++nt) {
            short8 b = *reinterpret_cast<const short8*>(Bs + (nt * 16 + l15) * 128 + co);
            ck[nt] = __builtin_amdgcn_mfma_f32_16x16x32_bf16(aa[kk2].s, b, ck[nt], 0, 0, 0);
        }
    }
    __syncthreads();
    // stage half 1 (K 128..255 = h part)
    #pragma unroll
    for (int it = 0; it < 8; ++it) {
        int i = it * 256 + tid;
        int row = i >> 4, c = i & 15;
        uint4 v = *reinterpret_cast<const uint4*>(woT + (size_t)row * 256 + 128 + c * 8);
        *reinterpret_cast<uint4*>(Bs + row * 128 + ((c ^ (row & 15)) << 3)) = v;
    }
    __syncthreads();
    #pragma unroll
    for (int kk2 = 0; kk2 < 4; ++kk2) {
        int co = ((kk2 * 4 + lk) ^ l15) << 3;
        #pragma unroll
        for (int nt = 0; nt < 8; ++nt) {
            short8 b = *reinterpret_cast<const short8*>(Bs + (nt * 16 + l15) * 128 + co);
            ck[nt] = __builtin_amdgcn_mfma_f32_16x16x32_bf16(ah[kk2].s, b, ck[nt], 0, 0, 0);
        }
    }

    // epilogue: bias + ReLU (in place), LN reduce over 16 l15-lanes, write
    #pragma unroll
    for (int nt = 0; nt < 8; ++nt) {
        float bo = wo_b[nt * 16 + l15];
        #pragma unroll
        for (int j = 0; j < 4; ++j)
            ck[nt][j] = fmaxf(ck[nt][j] + bo, 0.f);
    }
    float s1[4], s2[4];
    #pragma unroll
    for (int j = 0; j < 4; ++j) { s1[j] = 0.f; s2[j] = 0.f; }
    #pragma unroll
    for (int nt = 0; nt < 8; ++nt)
        #pragma unroll
        for (int j = 0; j < 4; ++j) {
            s1[j] += ck[nt][j];
            s2[j] = fmaf(ck[nt][j], ck[nt][j], s2[j]);
        }
    #pragma unroll
    for (int m = 1; m <= 8; m <<= 1)
        #pragma unroll
        for (int j = 0; j < 4; ++j) {
            s1[j] += __shfl_xor(s1[j], m, 64);
            s2[j] += __shfl_xor(s2[j], m, 64);
        }
    float mean[4], rstd[4];
    #pragma unroll
    for (int j = 0; j < 4; ++j) {
        mean[j] = s1[j] * (1.f / 128.f);
        float var = s2[j] * (1.f / 128.f) - mean[j] * mean[j];
        rstd[j] = rsqrtf(var + 1e-5f);
    }
    #pragma unroll
    for (int nt = 0; nt < 8; ++nt) {
        int col = nt * 16 + l15;
        float g = ln_g[col], lb = ln_b[col];
        #pragma unroll
        for (int j = 0; j < 4; ++j) {
            int row = r0 + lk * 4 + j;
            if (row < ndst)
                out[(size_t)row * 128 + col] = (ck[nt][j] - mean[j]) * rstd[j] * g + lb;
        }
    }
}

extern "C" void kernel_launch(void* const* d_in, const int* in_sizes, int n_in,
                              void* d_out, int out_size, void* d_ws, size_t ws_size,
                              hipStream_t stream) {
    const float* h      = (const float*)d_in[0];
    const float* dt     = (const float*)d_in[1];
    const float* ef     = (const float*)d_in[2];
    const float* time_w = (const float*)d_in[3];
    const float* time_b = (const float*)d_in[4];
    const float* wq_w   = (const float*)d_in[5];
    const float* wq_b   = (const float*)d_in[6];
    const float* wk_w   = (const float*)d_in[7];
    const float* wk_b   = (const float*)d_in[8];
    const float* wv_w   = (const float*)d_in[9];
    const float* wv_b   = (const float*)d_in[10];
    const float* wo_w   = (const float*)d_in[11];
    const float* wo_b   = (const float*)d_in[12];
    const float* ln_g   = (const float*)d_in[13];
    const float* ln_b   = (const float*)d_in[14];
    const int* nbr      = (const int*)d_in[15];
    const int* edst     = (const int*)d_in[16];

    int E    = in_sizes[1];
    int ndst = out_size / 128;
    int nblk = (ndst + 255) / 256;

    char* wsb = (char*)d_ws;
    float* qbias = (float*)wsb;                 wsb += 512;
    float* Q     = (float*)wsb;                 wsb += (size_t)ndst * 128 * 4;
    float* agg   = (float*)wsb;                 wsb += (size_t)ndst * 128 * 4;
    unsigned short* wkT  = (unsigned short*)wsb; wsb += 32768 * 2;
    unsigned short* wvT  = (unsigned short*)wsb; wsb += 32768 * 2;
    unsigned short* woT  = (unsigned short*)wsb; wsb += 32768 * 2;
    unsigned short* wqhT = (unsigned short*)wsb; wsb += 16384 * 2;
    unsigned short* wqlT = (unsigned short*)wsb; wsb += 16384 * 2;
    int* cnt    = (int*)wsb;                    wsb += (size_t)ndst * 4;
    int* fill   = (int*)wsb;                    wsb += (size_t)ndst * 4;
    int* rs     = (int*)wsb;                    wsb += (size_t)ndst * 4;
    int* bsum   = (int*)wsb;                    wsb += 1024;
    int* epos   = (int*)wsb;                    wsb += (size_t)E * 4;
    float2* att2 = (float2*)wsb;                wsb += (size_t)E * 8;
    unsigned short* Vbuf = (unsigned short*)wsb; wsb += (size_t)E * 128 * 2;

    hipMemsetAsync(cnt, 0, (size_t)ndst * 8, stream);  // cnt + fill (adjacent)
    k_prep<<<1, 128, 0, stream>>>(qbias, wq_w, wq_b, time_b);
    k_pack<<<128, 256, 0, stream>>>(wkT, wvT, woT, wqhT, wqlT, wk_w, wv_w, wo_w, wq_w);
    k_count<<<(E + 255) / 256, 256, 0, stream>>>(edst, cnt, E);
    k_scan1<<<nblk, 256, 0, stream>>>(cnt, rs, bsum, ndst);
    k_scan2<<<1, 256, 0, stream>>>(bsum, nblk);
    k_scan3<<<nblk, 256, 0, stream>>>(rs, bsum, ndst);
    k_scatter<<<(E + 255) / 256, 256, 0, stream>>>(edst, rs, fill, epos, E);
    k_q<<<(ndst + 63) / 64, 256, 0, stream>>>(Q, h, wqhT, wqlT, qbias, ndst);
    k_kvA<<<(E + 63) / 64, 256, 0, stream>>>(h, nbr, edst, dt, ef, time_w, time_b,
                                             wkT, wvT, wk_b, Q, epos, Vbuf, att2, ndst, E);
    k_agg<<<(ndst + 3) / 4, 256, 0, stream>>>(Vbuf, att2, rs, cnt, wv_b, agg, ndst);
    k_out<<<(ndst + 63) / 64, 256, 0, stream>>>(agg, h, woT, wo_b, ln_g, ln_b,
                                                (float*)d_out, ndst);
}

// Round 11
// 247.812 us; speedup vs baseline: 4.8737x; 1.0043x over previous
//
#include <hip/hip_runtime.h>
#include <hip/hip_bf16.h>
#include <math.h>

// TemporalTransformerConv (TGAT-like) for MI355X — round 11.
// k_kvA/k_q/k_out: 512-thread blocks, single full-table 64 KB LDS stage
// (swizzled), 2-3 barriers instead of 8. k_agg unrolled x4. k_prep merged
// into k_pack; k_scan3 folded into consumers (rs block-local + bsum[d>>8]).

using bf16 = __hip_bfloat16;
typedef __attribute__((ext_vector_type(8))) short short8;
typedef __attribute__((ext_vector_type(4))) float f32x4;

static __device__ __forceinline__ unsigned short bf16_bits(float x) {
    bf16 h = __float2bfloat16(x);
    unsigned short b;
    __builtin_memcpy(&b, &h, 2);
    return b;
}
static __device__ __forceinline__ unsigned pk2(float x, float y) {
    return (unsigned)bf16_bits(x) | ((unsigned)bf16_bits(y) << 16);
}
static __device__ __forceinline__ float bflo(unsigned u) {
    return __uint_as_float(u << 16);
}
static __device__ __forceinline__ float bfhi(unsigned u) {
    return __uint_as_float(u & 0xffff0000u);
}
union frag_u { short8 s; unsigned u[4]; };

// ------------------------- pack (+ qbias prep in block 0) -------------------------
__global__ void k_pack(unsigned short* wkT, unsigned short* wvT, unsigned short* woT,
                       unsigned short* wqhT, unsigned short* wqlT, float* qbias,
                       const float* __restrict__ wk_w, const float* __restrict__ wv_w,
                       const float* __restrict__ wo_w, const float* __restrict__ wq_w,
                       const float* __restrict__ wq_b, const float* __restrict__ time_b) {
    int idx = blockIdx.x * blockDim.x + threadIdx.x;  // 32768
    if (idx < 32768) {
        int n = idx >> 8, k = idx & 255;
        wkT[idx] = bf16_bits(wk_w[(size_t)k * 128 + n]);
        wvT[idx] = bf16_bits(wv_w[(size_t)k * 128 + n]);
        woT[idx] = bf16_bits(wo_w[(size_t)k * 128 + n]);
        if (idx < 16384) {
            int n2 = idx >> 7, k2 = idx & 127;
            float v = wq_w[(size_t)k2 * 128 + n2];
            unsigned short hb = bf16_bits(v);
            wqhT[idx] = hb;
            wqlT[idx] = bf16_bits(v - __uint_as_float((unsigned)hb << 16));
        }
        if (idx < 128) {
            float s = wq_b[idx];
            for (int j = 0; j < 64; ++j)
                s += cosf(time_b[j]) * wq_w[(128 + j) * 128 + idx];
            qbias[idx] = s;
        }
    }
}

// ------------------------- CSR slot assignment -------------------------
__global__ void k_count(const int* __restrict__ edst, int* cnt, int E) {
    int e = blockIdx.x * 256 + threadIdx.x;
    if (e < E) atomicAdd(&cnt[edst[e]], 1);
}

__global__ void k_scan1(const int* __restrict__ cnt, int* rs, int* bsum, int n) {
    __shared__ int s[256];
    int t = threadIdx.x;
    int i = blockIdx.x * 256 + t;
    int v = (i < n) ? cnt[i] : 0;
    s[t] = v;
    __syncthreads();
    for (int off = 1; off < 256; off <<= 1) {
        int x = (t >= off) ? s[t - off] : 0;
        __syncthreads();
        s[t] += x;
        __syncthreads();
    }
    if (i < n) rs[i] = s[t] - v;
    if (t == 255) bsum[blockIdx.x] = s[255];
}

__global__ void k_scan2(int* bsum, int nblk) {
    __shared__ int s[256];
    int t = threadIdx.x;
    int v = (t < nblk) ? bsum[t] : 0;
    s[t] = v;
    __syncthreads();
    for (int off = 1; off < 256; off <<= 1) {
        int x = (t >= off) ? s[t - off] : 0;
        __syncthreads();
        s[t] += x;
        __syncthreads();
    }
    if (t < nblk) bsum[t] = s[t] - v;
}

// epos[e] = global slot of edge e (rs is block-local; + bsum[d>>8])
__global__ void k_scatter(const int* __restrict__ edst, const int* __restrict__ rs,
                          const int* __restrict__ bsum, int* fill, int* epos, int E) {
    int e = blockIdx.x * 256 + threadIdx.x;
    if (e < E) {
        int d = edst[e];
        epos[e] = rs[d] + bsum[d >> 8] + atomicAdd(&fill[d], 1);
    }
}

// ------------------------- Q projection (split-bf16 MFMA, 512 thr) -------------------------
__global__ __launch_bounds__(512) void k_q(
    float* __restrict__ Q, const float* __restrict__ h,
    const unsigned short* __restrict__ wqhT, const unsigned short* __restrict__ wqlT,
    const float* __restrict__ qbias, int ndst)
{
    __shared__ unsigned short Bs[32768];  // 64 KB: Whi [0,16384), Wlo [16384,32768)
    int tid = threadIdx.x;
    int lane = tid & 63, l15 = lane & 15, lk = lane >> 4;
    int r0 = blockIdx.x * 128 + (tid >> 6) * 16;
    int ra = r0 + l15;
    int rc = (ra < ndst) ? ra : (ndst - 1);
    const float* hrow = h + (size_t)rc * 128;

    float4 hx[4][2];
    #pragma unroll
    for (int kk = 0; kk < 4; ++kk) {
        int c0 = kk * 32 + lk * 8;
        hx[kk][0] = *reinterpret_cast<const float4*>(hrow + c0);
        hx[kk][1] = *reinterpret_cast<const float4*>(hrow + c0 + 4);
    }

    // stage Whi + Wlo (2048 chunks each, 4+4 per thread)
    #pragma unroll
    for (int it = 0; it < 4; ++it) {
        int i = it * 512 + tid;
        int row = i >> 4, c = i & 15;
        int sw = ((c ^ (row & 15)) << 3);
        uint4 v = *reinterpret_cast<const uint4*>(wqhT + (size_t)row * 128 + c * 8);
        *reinterpret_cast<uint4*>(Bs + row * 128 + sw) = v;
        uint4 w = *reinterpret_cast<const uint4*>(wqlT + (size_t)row * 128 + c * 8);
        *reinterpret_cast<uint4*>(Bs + 16384 + row * 128 + sw) = w;
    }

    frag_u ah[4], al[4];
    #pragma unroll
    for (int kk = 0; kk < 4; ++kk) {
        float xs[8] = {hx[kk][0].x, hx[kk][0].y, hx[kk][0].z, hx[kk][0].w,
                       hx[kk][1].x, hx[kk][1].y, hx[kk][1].z, hx[kk][1].w};
        unsigned short hb[8];
        float lo[8];
        #pragma unroll
        for (int t = 0; t < 8; ++t) {
            hb[t] = bf16_bits(xs[t]);
            lo[t] = xs[t] - __uint_as_float((unsigned)hb[t] << 16);
        }
        #pragma unroll
        for (int t = 0; t < 4; ++t)
            ah[kk].u[t] = (unsigned)hb[2*t] | ((unsigned)hb[2*t+1] << 16);
        al[kk].u[0] = pk2(lo[0], lo[1]); al[kk].u[1] = pk2(lo[2], lo[3]);
        al[kk].u[2] = pk2(lo[4], lo[5]); al[kk].u[3] = pk2(lo[6], lo[7]);
    }

    f32x4 ck[8];
    #pragma unroll
    for (int nt = 0; nt < 8; ++nt) ck[nt] = (f32x4){0.f, 0.f, 0.f, 0.f};

    __syncthreads();
    #pragma unroll
    for (int kk2 = 0; kk2 < 4; ++kk2) {
        int co = ((kk2 * 4 + lk) ^ l15) << 3;
        #pragma unroll
        for (int nt = 0; nt < 8; ++nt) {
            int ro = (nt * 16 + l15) * 128;
            short8 bh = *reinterpret_cast<const short8*>(Bs + ro + co);
            short8 bl = *reinterpret_cast<const short8*>(Bs + 16384 + ro + co);
            ck[nt] = __builtin_amdgcn_mfma_f32_16x16x32_bf16(ah[kk2].s, bh, ck[nt], 0, 0, 0);
            ck[nt] = __builtin_amdgcn_mfma_f32_16x16x32_bf16(al[kk2].s, bh, ck[nt], 0, 0, 0);
            ck[nt] = __builtin_amdgcn_mfma_f32_16x16x32_bf16(ah[kk2].s, bl, ck[nt], 0, 0, 0);
        }
    }

    #pragma unroll
    for (int nt = 0; nt < 8; ++nt) {
        int col = nt * 16 + l15;
        float qb = qbias[col];
        #pragma unroll
        for (int j = 0; j < 4; ++j) {
            int row = r0 + lk * 4 + j;
            if (row < ndst) Q[(size_t)row * 128 + col] = ck[nt][j] + qb;
        }
    }
}

// ------------------------- edge pass (full-table LDS, 512 thr / 128 edges) -------------------------
// LDS layout: 128 rows x 256 elems (512 B); chunk c (16 B) stored at
// row*256 + ((c ^ (row&15))<<3). Read chunk kk*4+lk of row nt*16+l15.
__global__ __launch_bounds__(512) void k_kvA(
    const float* __restrict__ h, const int* __restrict__ nbr, const int* __restrict__ edst,
    const float* __restrict__ dt, const float* __restrict__ ef,
    const float* __restrict__ time_w, const float* __restrict__ time_b,
    const unsigned short* __restrict__ wkT, const unsigned short* __restrict__ wvT,
    const float* __restrict__ wk_b, const float* __restrict__ Q,
    const int* __restrict__ epos,
    unsigned short* __restrict__ Vbuf, float2* __restrict__ att2, int ndst, int E)
{
    __shared__ unsigned short Bs[32768];  // 64 KB
    int tid  = threadIdx.x;
    int lane = tid & 63;
    int l15  = lane & 15;
    int lk   = lane >> 4;
    int e0   = blockIdx.x * 128 + (tid >> 6) * 16;

    int  ea = e0 + l15;
    bool va = ea < E;
    int  na = va ? nbr[ea] : 0;
    float da = va ? dt[ea] : 0.f;
    const float* hrow = h + (size_t)(ndst + na) * 128;
    const float* erow = ef + (size_t)ea * 64;

    int dstr[4], pe[4];
    bool evv[4];
    #pragma unroll
    for (int j = 0; j < 4; ++j) {
        int ed = e0 + lk * 4 + j;
        evv[j]  = ed < E;
        dstr[j] = evv[j] ? edst[ed] : 0;
        pe[j]   = evv[j] ? epos[ed] : 0;
    }

    float4 hx[4][2], ex_[2][2];
    const float4 z4 = make_float4(0.f, 0.f, 0.f, 0.f);
    #pragma unroll
    for (int kk = 0; kk < 4; ++kk) {
        int c0 = kk * 32 + lk * 8;
        hx[kk][0] = va ? *reinterpret_cast<const float4*>(hrow + c0)     : z4;
        hx[kk][1] = va ? *reinterpret_cast<const float4*>(hrow + c0 + 4) : z4;
    }
    #pragma unroll
    for (int t = 0; t < 2; ++t) {
        int c = (4 + t) * 32 + lk * 8 - 128;
        ex_[t][0] = va ? *reinterpret_cast<const float4*>(erow + c)     : z4;
        ex_[t][1] = va ? *reinterpret_cast<const float4*>(erow + c + 4) : z4;
    }

    float qg[8][4];
    #pragma unroll
    for (int nt = 0; nt < 8; ++nt) {
        int gc = nt * 16 + l15;
        #pragma unroll
        for (int j = 0; j < 4; ++j)
            qg[nt][j] = Q[(size_t)dstr[j] * 128 + gc];
    }

    // stage full K table (4096 chunks, 8/thread)
    #pragma unroll
    for (int it = 0; it < 8; ++it) {
        int i = it * 512 + tid;
        int row = i >> 5, c = i & 31;
        uint4 v = *reinterpret_cast<const uint4*>(wkT + (size_t)row * 256 + c * 8);
        *reinterpret_cast<uint4*>(Bs + row * 256 + ((c ^ (row & 15)) << 3)) = v;
    }

    float tf[16];
    {
        int j0 = lk * 8;
        #pragma unroll
        for (int t = 0; t < 8; ++t) tf[t]     = __cosf(fmaf(da, time_w[j0 + t],      time_b[j0 + t]));
        #pragma unroll
        for (int t = 0; t < 8; ++t) tf[8 + t] = __cosf(fmaf(da, time_w[j0 + 32 + t], time_b[j0 + 32 + t]));
    }

    frag_u a[8];
    #pragma unroll
    for (int kk = 0; kk < 4; ++kk) {
        a[kk].u[0] = pk2(hx[kk][0].x, hx[kk][0].y); a[kk].u[1] = pk2(hx[kk][0].z, hx[kk][0].w);
        a[kk].u[2] = pk2(hx[kk][1].x, hx[kk][1].y); a[kk].u[3] = pk2(hx[kk][1].z, hx[kk][1].w);
    }
    #pragma unroll
    for (int t = 0; t < 2; ++t) {
        a[4+t].u[0] = pk2(ex_[t][0].x, ex_[t][0].y); a[4+t].u[1] = pk2(ex_[t][0].z, ex_[t][0].w);
        a[4+t].u[2] = pk2(ex_[t][1].x, ex_[t][1].y); a[4+t].u[3] = pk2(ex_[t][1].z, ex_[t][1].w);
    }
    a[6].u[0] = pk2(tf[0], tf[1]);  a[6].u[1] = pk2(tf[2], tf[3]);
    a[6].u[2] = pk2(tf[4], tf[5]);  a[6].u[3] = pk2(tf[6], tf[7]);
    a[7].u[0] = pk2(tf[8], tf[9]);  a[7].u[1] = pk2(tf[10], tf[11]);
    a[7].u[2] = pk2(tf[12], tf[13]); a[7].u[3] = pk2(tf[14], tf[15]);

    f32x4 ck[8];
    #pragma unroll
    for (int nt = 0; nt < 8; ++nt) ck[nt] = (f32x4){0.f, 0.f, 0.f, 0.f};

    __syncthreads();
    // K GEMM (uninterrupted, all LDS)
    #pragma unroll
    for (int kk2 = 0; kk2 < 8; ++kk2) {
        int co = ((kk2 * 4 + lk) ^ l15) << 3;
        #pragma unroll
        for (int nt = 0; nt < 8; ++nt) {
            short8 b = *reinterpret_cast<const short8*>(Bs + (nt * 16 + l15) * 256 + co);
            ck[nt] = __builtin_amdgcn_mfma_f32_16x16x32_bf16(a[kk2].s, b, ck[nt], 0, 0, 0);
        }
    }
    __syncthreads();
    // stage full V table (att section below overlaps the load latency)
    #pragma unroll
    for (int it = 0; it < 8; ++it) {
        int i = it * 512 + tid;
        int row = i >> 5, c = i & 31;
        uint4 v = *reinterpret_cast<const uint4*>(wvT + (size_t)row * 256 + c * 8);
        *reinterpret_cast<uint4*>(Bs + row * 256 + ((c ^ (row & 15)) << 3)) = v;
    }

    // att dot per head + 16-lane reduce, leaky, store
    float p0[4], p1[4];
    #pragma unroll
    for (int j = 0; j < 4; ++j) { p0[j] = 0.f; p1[j] = 0.f; }
    #pragma unroll
    for (int nt = 0; nt < 8; ++nt) {
        float kb = wk_b[nt * 16 + l15];
        #pragma unroll
        for (int j = 0; j < 4; ++j) {
            float t = (ck[nt][j] + kb) * qg[nt][j];
            if (nt < 4) p0[j] += t; else p1[j] += t;
        }
    }
    #pragma unroll
    for (int m = 1; m <= 8; m <<= 1)
        #pragma unroll
        for (int j = 0; j < 4; ++j) {
            p0[j] += __shfl_xor(p0[j], m, 64);
            p1[j] += __shfl_xor(p1[j], m, 64);
        }
    if (l15 == 0) {
        #pragma unroll
        for (int j = 0; j < 4; ++j)
            if (evv[j]) {
                float r0 = p0[j]; r0 = (r0 >= 0.f) ? r0 : 0.2f * r0;
                float r1 = p1[j]; r1 = (r1 >= 0.f) ? r1 : 0.2f * r1;
                att2[pe[j]] = make_float2(r0, r1);
            }
    }

    f32x4 cv[8];
    #pragma unroll
    for (int nt = 0; nt < 8; ++nt) cv[nt] = (f32x4){0.f, 0.f, 0.f, 0.f};
    __syncthreads();
    // V GEMM
    #pragma unroll
    for (int kk2 = 0; kk2 < 8; ++kk2) {
        int co = ((kk2 * 4 + lk) ^ l15) << 3;
        #pragma unroll
        for (int nt = 0; nt < 8; ++nt) {
            short8 b = *reinterpret_cast<const short8*>(Bs + (nt * 16 + l15) * 256 + co);
            cv[nt] = __builtin_amdgcn_mfma_f32_16x16x32_bf16(a[kk2].s, b, cv[nt], 0, 0, 0);
        }
    }

    #pragma unroll
    for (int j = 0; j < 4; ++j)
        if (evv[j]) {
            uint4 val;
            val.x = pk2(cv[0][j], cv[1][j]);
            val.y = pk2(cv[2][j], cv[3][j]);
            val.z = pk2(cv[4][j], cv[5][j]);
            val.w = pk2(cv[6][j], cv[7][j]);
            *reinterpret_cast<uint4*>(Vbuf + (size_t)pe[j] * 128 + l15 * 8) = val;
        }
}

// ------------------------- streaming segment reduction (unrolled x4) -------------------------
__global__ __launch_bounds__(256) void k_agg(
    const unsigned short* __restrict__ Vbuf, const float2* __restrict__ att2,
    const int* __restrict__ rs, const int* __restrict__ bsum, const int* __restrict__ cnt,
    const float* __restrict__ wv_b, float* __restrict__ agg, int ndst)
{
    int w = threadIdx.x >> 6, lane = threadIdx.x & 63;
    int d = blockIdx.x * 4 + w;
    if (d >= ndst) return;
    int p0 = lane * 2, p1 = p0 + 1;
    int c0 = ((p0 & 7) << 4) + (p0 >> 3);
    int c1 = ((p1 & 7) << 4) + (p1 >> 3);
    bool h0 = (p0 & 4) != 0, h1 = (p1 & 4) != 0;
    int base = rs[d] + bsum[d >> 8], n = cnt[d];
    const unsigned* V32 = reinterpret_cast<const unsigned*>(Vbuf);
    float den0 = 0.f, den1 = 0.f, acc0 = 0.f, acc1 = 0.f;
    int i = 0;
    for (; i + 4 <= n; i += 4) {
        size_t r = (size_t)(base + i);
        float2 a0 = att2[r], a1 = att2[r+1], a2 = att2[r+2], a3 = att2[r+3];
        unsigned w0 = V32[r*64 + lane], w1 = V32[(r+1)*64 + lane];
        unsigned w2 = V32[(r+2)*64 + lane], w3 = V32[(r+3)*64 + lane];
        float e00 = __expf(a0.x), e01 = __expf(a0.y);
        float e10 = __expf(a1.x), e11 = __expf(a1.y);
        float e20 = __expf(a2.x), e21 = __expf(a2.y);
        float e30 = __expf(a3.x), e31 = __expf(a3.y);
        den0 += e00 + e10 + e20 + e30;
        den1 += e01 + e11 + e21 + e31;
        acc0 = fmaf(h0 ? e01 : e00, bflo(w0), acc0);
        acc1 = fmaf(h1 ? e01 : e00, bfhi(w0), acc1);
        acc0 = fmaf(h0 ? e11 : e10, bflo(w1), acc0);
        acc1 = fmaf(h1 ? e11 : e10, bfhi(w1), acc1);
        acc0 = fmaf(h0 ? e21 : e20, bflo(w2), acc0);
        acc1 = fmaf(h1 ? e21 : e20, bfhi(w2), acc1);
        acc0 = fmaf(h0 ? e31 : e30, bflo(w3), acc0);
        acc1 = fmaf(h1 ? e31 : e30, bfhi(w3), acc1);
    }
    for (; i < n; ++i) {
        size_t r = (size_t)(base + i);
        float2 at = att2[r];
        float ex0 = __expf(at.x), ex1 = __expf(at.y);
        den0 += ex0; den1 += ex1;
        unsigned vv = V32[r*64 + lane];
        acc0 = fmaf(h0 ? ex1 : ex0, bflo(vv), acc0);
        acc1 = fmaf(h1 ? ex1 : ex0, bfhi(vv), acc1);
    }
    float o0 = 0.f, o1 = 0.f;
    if (n > 0) {
        o0 = acc0 / (h0 ? den1 : den0) + wv_b[c0];
        o1 = acc1 / (h1 ? den1 : den0) + wv_b[c1];
    }
    agg[(size_t)d * 128 + c0] = o0;
    agg[(size_t)d * 128 + c1] = o1;
}

// ------------------------- output (bf16 MFMA + ReLU + LayerNorm, 512 thr) -------------------------
__global__ __launch_bounds__(512) void k_out(
    const float* __restrict__ agg, const float* __restrict__ h,
    const unsigned short* __restrict__ woT, const float* __restrict__ wo_b,
    const float* __restrict__ ln_g, const float* __restrict__ ln_b,
    float* __restrict__ out, int ndst)
{
    __shared__ unsigned short Bs[32768];  // 64 KB full woT
    int tid = threadIdx.x;
    int lane = tid & 63, l15 = lane & 15, lk = lane >> 4;
    int r0 = blockIdx.x * 128 + (tid >> 6) * 16;
    int ra = r0 + l15;
    int rc = (ra < ndst) ? ra : (ndst - 1);
    const float* arow = agg + (size_t)rc * 128;
    const float* hrow = h + (size_t)rc * 128;

    float4 ax[4][2], hx[4][2];
    #pragma unroll
    for (int kk = 0; kk < 4; ++kk) {
        int c0 = kk * 32 + lk * 8;
        ax[kk][0] = *reinterpret_cast<const float4*>(arow + c0);
        ax[kk][1] = *reinterpret_cast<const float4*>(arow + c0 + 4);
        hx[kk][0] = *reinterpret_cast<const float4*>(hrow + c0);
        hx[kk][1] = *reinterpret_cast<const float4*>(hrow + c0 + 4);
    }

    // stage full woT (4096 chunks)
    #pragma unroll
    for (int it = 0; it < 8; ++it) {
        int i = it * 512 + tid;
        int row = i >> 5, c = i & 31;
        uint4 v = *reinterpret_cast<const uint4*>(woT + (size_t)row * 256 + c * 8);
        *reinterpret_cast<uint4*>(Bs + row * 256 + ((c ^ (row & 15)) << 3)) = v;
    }

    frag_u aa[4], ah[4];
    #pragma unroll
    for (int kk = 0; kk < 4; ++kk) {
        aa[kk].u[0] = pk2(ax[kk][0].x, ax[kk][0].y); aa[kk].u[1] = pk2(ax[kk][0].z, ax[kk][0].w);
        aa[kk].u[2] = pk2(ax[kk][1].x, ax[kk][1].y); aa[kk].u[3] = pk2(ax[kk][1].z, ax[kk][1].w);
        ah[kk].u[0] = pk2(hx[kk][0].x, hx[kk][0].y); ah[kk].u[1] = pk2(hx[kk][0].z, hx[kk][0].w);
        ah[kk].u[2] = pk2(hx[kk][1].x, hx[kk][1].y); ah[kk].u[3] = pk2(hx[kk][1].z, hx[kk][1].w);
    }

    f32x4 ck[8];
    #pragma unroll
    for (int nt = 0; nt < 8; ++nt) ck[nt] = (f32x4){0.f, 0.f, 0.f, 0.f};

    __syncthreads();
    #pragma unroll
    for (int kk2 = 0; kk2 < 4; ++kk2) {
        int coA = ((kk2 * 4 + lk) ^ l15) << 3;          // chunks 0..15 (agg half)
        int coH = (((16 + kk2 * 4 + lk)) ^ l15) << 3;   // chunks 16..31 (h half)
        #pragma unroll
        for (int nt = 0; nt < 8; ++nt) {
            int ro = (nt * 16 + l15) * 256;
            short8 bA = *reinterpret_cast<const short8*>(Bs + ro + coA);
            short8 bH = *reinterpret_cast<const short8*>(Bs + ro + coH);
            ck[nt] = __builtin_amdgcn_mfma_f32_16x16x32_bf16(aa[kk2].s, bA, ck[nt], 0, 0, 0);
            ck[nt] = __builtin_amdgcn_mfma_f32_16x16x32_bf16(ah[kk2].s, bH, ck[nt], 0, 0, 0);
        }
    }

    #pragma unroll
    for (int nt = 0; nt < 8; ++nt) {
        float bo = wo_b[nt * 16 + l15];
        #pragma unroll
        for (int j = 0; j < 4; ++j)
            ck[nt][j] = fmaxf(ck[nt][j] + bo, 0.f);
    }
    float s1[4], s2[4];
    #pragma unroll
    for (int j = 0; j < 4; ++j) { s1[j] = 0.f; s2[j] = 0.f; }
    #pragma unroll
    for (int nt = 0; nt < 8; ++nt)
        #pragma unroll
        for (int j = 0; j < 4; ++j) {
            s1[j] += ck[nt][j];
            s2[j] = fmaf(ck[nt][j], ck[nt][j], s2[j]);
        }
    #pragma unroll
    for (int m = 1; m <= 8; m <<= 1)
        #pragma unroll
        for (int j = 0; j < 4; ++j) {
            s1[j] += __shfl_xor(s1[j], m, 64);
            s2[j] += __shfl_xor(s2[j], m, 64);
        }
    float mean[4], rstd[4];
    #pragma unroll
    for (int j = 0; j < 4; ++j) {
        mean[j] = s1[j] * (1.f / 128.f);
        float var = s2[j] * (1.f / 128.f) - mean[j] * mean[j];
        rstd[j] = rsqrtf(var + 1e-5f);
    }
    #pragma unroll
    for (int nt = 0; nt < 8; ++nt) {
        int col = nt * 16 + l15;
        float g = ln_g[col], lb = ln_b[col];
        #pragma unroll
        for (int j = 0; j < 4; ++j) {
            int row = r0 + lk * 4 + j;
            if (row < ndst)
                out[(size_t)row * 128 + col] = (ck[nt][j] - mean[j]) * rstd[j] * g + lb;
        }
    }
}

extern "C" void kernel_launch(void* const* d_in, const int* in_sizes, int n_in,
                              void* d_out, int out_size, void* d_ws, size_t ws_size,
                              hipStream_t stream) {
    const float* h      = (const float*)d_in[0];
    const float* dt     = (const float*)d_in[1];
    const float* ef     = (const float*)d_in[2];
    const float* time_w = (const float*)d_in[3];
    const float* time_b = (const float*)d_in[4];
    const float* wq_w   = (const float*)d_in[5];
    const float* wq_b   = (const float*)d_in[6];
    const float* wk_w   = (const float*)d_in[7];
    const float* wk_b   = (const float*)d_in[8];
    const float* wv_w   = (const float*)d_in[9];
    const float* wv_b   = (const float*)d_in[10];
    const float* wo_w   = (const float*)d_in[11];
    const float* wo_b   = (const float*)d_in[12];
    const float* ln_g   = (const float*)d_in[13];
    const float* ln_b   = (const float*)d_in[14];
    const int* nbr      = (const int*)d_in[15];
    const int* edst     = (const int*)d_in[16];

    int E    = in_sizes[1];
    int ndst = out_size / 128;
    int nblk = (ndst + 255) / 256;

    char* wsb = (char*)d_ws;
    float* qbias = (float*)wsb;                 wsb += 512;
    float* Q     = (float*)wsb;                 wsb += (size_t)ndst * 128 * 4;
    float* agg   = (float*)wsb;                 wsb += (size_t)ndst * 128 * 4;
    unsigned short* wkT  = (unsigned short*)wsb; wsb += 32768 * 2;
    unsigned short* wvT  = (unsigned short*)wsb; wsb += 32768 * 2;
    unsigned short* woT  = (unsigned short*)wsb; wsb += 32768 * 2;
    unsigned short* wqhT = (unsigned short*)wsb; wsb += 16384 * 2;
    unsigned short* wqlT = (unsigned short*)wsb; wsb += 16384 * 2;
    int* cnt    = (int*)wsb;                    wsb += (size_t)ndst * 4;
    int* fill   = (int*)wsb;                    wsb += (size_t)ndst * 4;
    int* rs     = (int*)wsb;                    wsb += (size_t)ndst * 4;
    int* bsum   = (int*)wsb;                    wsb += 1024;
    int* epos   = (int*)wsb;                    wsb += (size_t)E * 4;
    float2* att2 = (float2*)wsb;                wsb += (size_t)E * 8;
    unsigned short* Vbuf = (unsigned short*)wsb; wsb += (size_t)E * 128 * 2;

    hipMemsetAsync(cnt, 0, (size_t)ndst * 8, stream);  // cnt + fill (adjacent)
    k_pack<<<128, 256, 0, stream>>>(wkT, wvT, woT, wqhT, wqlT, qbias,
                                    wk_w, wv_w, wo_w, wq_w, wq_b, time_b);
    k_count<<<(E + 255) / 256, 256, 0, stream>>>(edst, cnt, E);
    k_scan1<<<nblk, 256, 0, stream>>>(cnt, rs, bsum, ndst);
    k_scan2<<<1, 256, 0, stream>>>(bsum, nblk);
    k_scatter<<<(E + 255) / 256, 256, 0, stream>>>(edst, rs, bsum, fill, epos, E);
    k_q<<<(ndst + 127) / 128, 512, 0, stream>>>(Q, h, wqhT, wqlT, qbias, ndst);
    k_kvA<<<(E + 127) / 128, 512, 0, stream>>>(h, nbr, edst, dt, ef, time_w, time_b,
                                               wkT, wvT, wk_b, Q, epos, Vbuf, att2, ndst, E);
    k_agg<<<(ndst + 3) / 4, 256, 0, stream>>>(Vbuf, att2, rs, bsum, cnt, wv_b, agg, ndst);
    k_out<<<(ndst + 127) / 128, 512, 0, stream>>>(agg, h, woT, wo_b, ln_g, ln_b,
                                                  (float*)d_out, ndst);
}